// Round 11
// baseline (4664.910 us; speedup 1.0000x reference)
//
#include <hip/hip_runtime.h>
#include <hip/hip_bf16.h>
#include <float.h>
#include <type_traits>

#define NROW 131072

using f16x8 = __attribute__((ext_vector_type(8))) _Float16;
using f16x4 = __attribute__((ext_vector_type(4))) _Float16;
using s16x8 = __attribute__((ext_vector_type(8))) short;
using f32x4 = __attribute__((ext_vector_type(4))) float;

__device__ __forceinline__ f32x4 mfma32(f16x8 a, f16x8 b, f32x4 c) {
    return __builtin_amdgcn_mfma_f32_16x16x32_f16(a, b, c, 0, 0, 0);
}
__device__ __forceinline__ f32x4 mfma32(s16x8 a, s16x8 b, f32x4 c) {
    return __builtin_amdgcn_mfma_f32_16x16x32_bf16(a, b, c, 0, 0, 0);
}

__device__ __forceinline__ short f2bf(float f) {
    unsigned u = __builtin_bit_cast(unsigned, f);
    u += 0x7fffu + ((u >> 16) & 1u);
    return (short)(u >> 16);
}

__device__ __forceinline__ void gload16(const void* g, void* l) {
    __builtin_amdgcn_global_load_lds(
        (const __attribute__((address_space(1))) void*)g,
        (__attribute__((address_space(3))) void*)l, 16, 0, 0);
}

// ---------------------------------------------------------------------------
// MFMA GEMM v8 = v7 (r10) with E0/E1 moved to BK=32 for 4 blocks/CU.
// Rationale: r10's E0 (BK=64, 64KB LDS, 2 blk/CU) spends ~55% of each k-step
// in the vmcnt(0)+barrier drain; m114 says resident-block TLP is what hides
// that drain. BK=32 halves LDS (32KB -> 4 blk/CU, 50% occupancy) at the cost
// of 2x barriers. r8 showed BK-halving at FIXED occupancy costs ~13%; this
// tests the occupancy-doubled quadrant.
//  - SPLIT rows: 128B = 8 slots (hi 0-3, lo 4-7), phys slot = logical ^
//    (row&7) (r7-proven, 0 conflicts). bf16 rows 128B, 8 slots, ^(row&7).
//    Inverse swizzle on per-lane GLOBAL source, LDS dest linear (rule 21).
//  - Coalesced LDS-staged epilogue (r10-proven: kills 2x write amplification)
//  - Stage pointers precomputed once; XCD-chunked bijective remap.
// A:[M][K] ET row-major, Bt:[N][K]. OUT: 0=f32, 1=fp16 hi/lo split
// (lo pre-scaled 4096), 2=bf16. Waves fixed 2x2.
// ---------------------------------------------------------------------------
template<typename ET, bool SPLIT, int OUT, int BM, int BN, int BK, bool RELU>
__global__ __launch_bounds__(256,
    ((BM + BN) * (SPLIT ? BK * 4 : BK * 2)) <= 32768 ? 4 :
    (((BM + BN) * (SPLIT ? BK * 4 : BK * 2)) <= 49152 ? 3 : 2))
void mm_mfma(
    const ET* __restrict__ Ah, const ET* __restrict__ Al,
    const ET* __restrict__ Bh, const ET* __restrict__ Bl,
    const float* __restrict__ bias,
    void* __restrict__ O0, void* __restrict__ O1,
    int M, int N, int K)
{
    constexpr int WTM = BM / 2, WTN = BN / 2;
    constexpr int MF = WTM / 16, NF = WTN / 16;
    constexpr int KS = BK / 32;
    constexpr int RB = SPLIT ? BK * 4 : BK * 2;   // row bytes
    constexpr int SLOTS = RB / 16;
    constexpr int SMASK = SLOTS - 1;
    constexpr int RPI = 1024 / RB;                // rows per staging inst
    constexpr int IA = BM * RB / 1024;
    constexpr int IB = BN * RB / 1024;
    constexpr int IT = IA + IB;
    constexpr int IPW = IT / 4;
    static_assert(IT % 4 == 0, "staging insts must split across 4 waves");
    using VT = typename std::conditional<std::is_same<ET, _Float16>::value,
                                         f16x8, s16x8>::type;

    __shared__ __align__(16) char smem[(BM + BN) * RB];

    const int tid  = threadIdx.x;
    const int lane = tid & 63;
    const int wave = tid >> 6;
    const int wm = wave >> 1, wn = wave & 1;

    // XCD-chunked bijective remap (all grids have nwg % 8 == 0)
    int gx = gridDim.x, nwg = gx * gridDim.y;
    int id = blockIdx.y * gx + blockIdx.x;
    int l  = (nwg & 7) ? id : ((id & 7) * (nwg >> 3) + (id >> 3));
    const int bm = (l / gx) * BM;
    const int bn = (l % gx) * BN;

    // ---- precompute staging pointers (register arrays, static indices)
    const int r_loc = lane / SLOTS;
    const int p     = lane % SLOTS;
    const char* gsrc[IPW];
    int ldst[IPW];
#pragma unroll
    for (int i = 0; i < IPW; ++i) {
        int inst = wave * IPW + i;
        bool isA = inst < IA;
        int li   = isA ? inst : inst - IA;
        int row  = li * RPI + r_loc;
        int g    = p ^ (row & SMASK);
        int grow = (isA ? bm : bn) + row;
        const ET* s; int col;
        if constexpr (SPLIT) {
            s   = (g < SLOTS / 2) ? (isA ? Ah : Bh) : (isA ? Al : Bl);
            col = (g & (SLOTS / 2 - 1)) * 8;
        } else {
            s   = isA ? Ah : Bh;
            col = g * 8;
        }
        gsrc[i] = (const char*)(s + (size_t)grow * K + col);
        ldst[i] = (isA ? 0 : BM * RB) + li * 1024;
    }

    char* sA = smem;
    char* sB = smem + BM * RB;

    f32x4 acc1[MF][NF];
    f32x4 acc2[SPLIT ? MF : 1][SPLIT ? NF : 1];
#pragma unroll
    for (int m = 0; m < MF; ++m)
#pragma unroll
        for (int n = 0; n < NF; ++n) {
            acc1[m][n] = f32x4{0.f, 0.f, 0.f, 0.f};
            if constexpr (SPLIT) acc2[m][n] = f32x4{0.f, 0.f, 0.f, 0.f};
        }

    const int kg  = lane >> 4;     // k-group 0..3
    const int l15 = lane & 15;

    for (int k0 = 0; k0 < K; k0 += BK) {
#pragma unroll
        for (int i = 0; i < IPW; ++i)
            gload16(gsrc[i] + (size_t)k0 * sizeof(ET), smem + ldst[i]);
        __syncthreads();
#pragma unroll
        for (int ks = 0; ks < KS; ++ks) {
            const int hslot = ks * 4 + kg;
            VT bh_[NF]; VT bl_[SPLIT ? NF : 1];
#pragma unroll
            for (int n = 0; n < NF; ++n) {
                int nr = wn * WTN + n * 16 + l15;
                bh_[n] = *(const VT*)(sB + nr * RB + ((hslot ^ (nr & SMASK)) << 4));
                if constexpr (SPLIT)
                    bl_[n] = *(const VT*)(sB + nr * RB +
                              (((SLOTS / 2 + hslot) ^ (nr & SMASK)) << 4));
            }
#pragma unroll
            for (int m = 0; m < MF; ++m) {
                int mr = wm * WTM + m * 16 + l15;
                VT a_h = *(const VT*)(sA + mr * RB + ((hslot ^ (mr & SMASK)) << 4));
                VT a_l;
                if constexpr (SPLIT)
                    a_l = *(const VT*)(sA + mr * RB +
                          (((SLOTS / 2 + hslot) ^ (mr & SMASK)) << 4));
#pragma unroll
                for (int n = 0; n < NF; ++n) {
                    acc1[m][n] = mfma32(a_h, bh_[n], acc1[m][n]);
                    if constexpr (SPLIT) {
                        acc2[m][n] = mfma32(a_l, bh_[n], acc2[m][n]);
                        acc2[m][n] = mfma32(a_h, bl_[n], acc2[m][n]);
                    }
                }
            }
        }
        __syncthreads();
    }

    // ---------------- epilogue: LDS-staged coalesced stores ----------------
    constexpr int OELT = (OUT == 0) ? 4 : 2;      // output element bytes
    constexpr int ROWB = WTN * OELT;              // logical row bytes
    constexpr int RSTR = ROWB + 16;               // padded stride
    constexpr int NRG  = (OUT == 1) ? 2 : 1;
    constexpr int SCR  = 16 * RSTR * NRG;         // per-wave scratch bytes
    char* wscr = smem + wave * SCR;
    const int colb = bn + wn * WTN;

#pragma unroll
    for (int m = 0; m < MF; ++m) {
#pragma unroll
        for (int n = 0; n < NF; ++n) {
            int cl = n * 16 + l15;
            float bv = bias[colb + cl];
            f32x4 v = acc1[m][n];
            if constexpr (SPLIT) {
                f32x4 v2 = acc2[m][n];
#pragma unroll
                for (int r = 0; r < 4; ++r) v[r] += v2[r] * (1.0f / 4096.0f);
            }
#pragma unroll
            for (int r = 0; r < 4; ++r) {
                float f = v[r] + bv;
                if constexpr (RELU) f = fmaxf(f, 0.f);
                int lr = kg * 4 + r;
                if constexpr (OUT == 0) {
                    *(float*)(wscr + lr * RSTR + cl * 4) = f;
                } else if constexpr (OUT == 1) {
                    _Float16 hi = (_Float16)f;
                    _Float16 lo = (_Float16)((f - (float)hi) * 4096.f);
                    *(_Float16*)(wscr + lr * RSTR + cl * 2) = hi;
                    *(_Float16*)(wscr + 16 * RSTR + lr * RSTR + cl * 2) = lo;
                } else {
                    *(short*)(wscr + lr * RSTR + cl * 2) = f2bf(f);
                }
            }
        }
        asm volatile("s_waitcnt lgkmcnt(0)" ::: "memory");
        __builtin_amdgcn_sched_barrier(0);

        constexpr int LPR = ROWB / 16;
        constexpr int RPT = 64 / LPR;
        const int rr = lane / LPR;
        const int jj = lane % LPR;
#pragma unroll
        for (int g = 0; g < 16 / RPT; ++g) {
            int lr = g * RPT + rr;
            size_t grow = (size_t)(bm + wm * WTM + m * 16 + lr);
            if constexpr (OUT == 0) {
                float4 vv = *(const float4*)(wscr + lr * RSTR + jj * 16);
                *(float4*)((float*)O0 + grow * N + colb + jj * 4) = vv;
            } else if constexpr (OUT == 1) {
                f16x8 hv = *(const f16x8*)(wscr + lr * RSTR + jj * 16);
                f16x8 lv = *(const f16x8*)(wscr + 16 * RSTR + lr * RSTR + jj * 16);
                *(f16x8*)((_Float16*)O0 + grow * N + colb + jj * 8) = hv;
                *(f16x8*)((_Float16*)O1 + grow * N + colb + jj * 8) = lv;
            } else {
                s16x8 vv = *(const s16x8*)(wscr + lr * RSTR + jj * 16);
                *(s16x8*)((short*)O0 + grow * N + colb + jj * 8) = vv;
            }
        }
        asm volatile("s_waitcnt lgkmcnt(0)" ::: "memory");
        __builtin_amdgcn_sched_barrier(0);
    }
}

// ---------------------------------------------------------------------------
// x (f32) -> xh, xl (fp16, lo pre-scaled by 4096)
// ---------------------------------------------------------------------------
__global__ __launch_bounds__(256) void prep_x(
    const float* __restrict__ x, _Float16* __restrict__ xh, _Float16* __restrict__ xl)
{
    const size_t total = (size_t)NROW * 768 / 4;
    for (size_t i = (size_t)blockIdx.x * 256 + threadIdx.x; i < total;
         i += (size_t)gridDim.x * 256) {
        float4 v = ((const float4*)x)[i];
        f16x4 h, ll;
        h[0] = (_Float16)v.x; h[1] = (_Float16)v.y;
        h[2] = (_Float16)v.z; h[3] = (_Float16)v.w;
        ll[0] = (_Float16)((v.x - (float)h[0]) * 4096.f);
        ll[1] = (_Float16)((v.y - (float)h[1]) * 4096.f);
        ll[2] = (_Float16)((v.z - (float)h[2]) * 4096.f);
        ll[3] = (_Float16)((v.w - (float)h[3]) * 4096.f);
        ((f16x4*)xh)[i] = h;
        ((f16x4*)xl)[i] = ll;
    }
}

// ---------------------------------------------------------------------------
// W [K][N] f32 -> transposed Th/Tl [N][K] (fp16 split or bf16)
// ---------------------------------------------------------------------------
template<bool SPLIT>
__global__ __launch_bounds__(256) void prep_w(
    const float* __restrict__ W, void* __restrict__ Th, void* __restrict__ Tl,
    int K, int N)
{
    __shared__ float t[32][33];
    const int bn = blockIdx.x * 32, bk = blockIdx.y * 32;
    const int lx = threadIdx.x & 31, ly = threadIdx.x >> 5;
#pragma unroll
    for (int i = 0; i < 32; i += 8)
        t[ly + i][lx] = W[(size_t)(bk + ly + i) * N + bn + lx];
    __syncthreads();
#pragma unroll
    for (int i = 0; i < 32; i += 8) {
        float v = t[lx][ly + i];
        size_t o = (size_t)(bn + ly + i) * K + bk + lx;
        if constexpr (SPLIT) {
            _Float16 hi = (_Float16)v;
            _Float16 lo = (_Float16)((v - (float)hi) * 4096.f);
            ((_Float16*)Th)[o] = hi;
            ((_Float16*)Tl)[o] = lo;
        } else {
            ((short*)Th)[o] = f2bf(v);
        }
    }
}

// ---------------------------------------------------------------------------
// Codebook prep: f32 [4][256][64] -> fp16 hi/lo [4][256][64] PRE-SWIZZLED
// (slot s of code c holds dims (s ^ (c&7))*8 .. +8) + f32 cnorm [4][256].
// ---------------------------------------------------------------------------
__global__ __launch_bounds__(256) void prep_cb(
    const float* __restrict__ cb, _Float16* __restrict__ ch,
    _Float16* __restrict__ cl, float* __restrict__ cn)
{
    const int lvl = blockIdx.x;
    const int code = threadIdx.x;
    const float* src = cb + ((size_t)lvl * 256 + code) * 64;
    _Float16* dh = ch + ((size_t)lvl * 256 + code) * 64;
    _Float16* dl = cl + ((size_t)lvl * 256 + code) * 64;
    float s = 0.f;
#pragma unroll
    for (int d = 0; d < 64; ++d) s += src[d] * src[d];
    cn[lvl * 256 + code] = s;
#pragma unroll
    for (int slot = 0; slot < 8; ++slot) {
        int ss = slot ^ (code & 7);
#pragma unroll
        for (int i = 0; i < 8; ++i) {
            float v = src[ss * 8 + i];
            _Float16 h = (_Float16)v;
            dh[slot * 8 + i] = h;
            dl[slot * 8 + i] = (_Float16)((v - (float)h) * 4096.f);
        }
    }
}

// ---------------------------------------------------------------------------
// MFMA residual quantizer (unchanged — measured off top-5).
// ---------------------------------------------------------------------------
__global__ __launch_bounds__(256, 2) void rq_mfma(
    const float* __restrict__ z,
    const _Float16* __restrict__ cbh_g, const _Float16* __restrict__ cbl_g,
    const float* __restrict__ cnorm_g,
    short* __restrict__ xqb, float* __restrict__ idx_out,
    float* __restrict__ loss1)
{
    __shared__ __align__(16) char sH[32768];
    __shared__ __align__(16) char sL[32768];
    __shared__ __align__(16) float sCN[256];

    const int tid  = threadIdx.x;
    const int lane = tid & 63;
    const int wave = tid >> 6;
    const int l15  = lane & 15;
    const int kgrp = lane >> 4;
    const int d0   = kgrp * 8;

    const size_t rowbase = (size_t)blockIdx.x * 256 + wave * 64;

    float rf[4][16];
#pragma unroll
    for (int t = 0; t < 4; ++t) {
        const float* zr = z + (rowbase + t * 16 + l15) * 64;
#pragma unroll
        for (int kf = 0; kf < 2; ++kf) {
            float4 v0 = *(const float4*)(zr + kf * 32 + d0);
            float4 v1 = *(const float4*)(zr + kf * 32 + d0 + 4);
            rf[t][kf * 8 + 0] = v0.x; rf[t][kf * 8 + 1] = v0.y;
            rf[t][kf * 8 + 2] = v0.z; rf[t][kf * 8 + 3] = v0.w;
            rf[t][kf * 8 + 4] = v1.x; rf[t][kf * 8 + 5] = v1.y;
            rf[t][kf * 8 + 6] = v1.z; rf[t][kf * 8 + 7] = v1.w;
        }
    }

    float lsum = 0.f;

    for (int lvl = 0; lvl < 4; ++lvl) {
        __syncthreads();
        {
            const char* gh = (const char*)(cbh_g + (size_t)lvl * 16384);
            const char* gl = (const char*)(cbl_g + (size_t)lvl * 16384);
            const char* gc = (const char*)(cnorm_g + lvl * 256);
            for (int i = wave; i < 65; i += 4) {
                if (i < 32)      gload16(gh + (size_t)i * 1024 + lane * 16, sH + i * 1024);
                else if (i < 64) gload16(gl + (size_t)(i - 32) * 1024 + lane * 16, sL + (i - 32) * 1024);
                else             gload16(gc + lane * 16, (char*)sCN);
            }
        }
        __syncthreads();

        float cn[16];
#pragma unroll
        for (int nf = 0; nf < 16; ++nf) cn[nf] = sCN[nf * 16 + l15];

        for (int t = 0; t < 4; ++t) {
            f16x8 rh0, rh1, rl0, rl1;
#pragma unroll
            for (int i = 0; i < 8; ++i) {
                _Float16 h = (_Float16)rf[t][i];
                rh0[i] = h;
                rl0[i] = (_Float16)((rf[t][i] - (float)h) * 4096.f);
                _Float16 h1 = (_Float16)rf[t][8 + i];
                rh1[i] = h1;
                rl1[i] = (_Float16)((rf[t][8 + i] - (float)h1) * 4096.f);
            }

            float dmin[4]; int imin[4];
#pragma unroll
            for (int j = 0; j < 4; ++j) { dmin[j] = FLT_MAX; imin[j] = 0; }

#pragma unroll
            for (int half = 0; half < 2; ++half) {
                f32x4 a1[8], a2[8];
#pragma unroll
                for (int q = 0; q < 8; ++q) {
                    a1[q] = f32x4{0.f, 0.f, 0.f, 0.f};
                    a2[q] = f32x4{0.f, 0.f, 0.f, 0.f};
                }
#pragma unroll
                for (int q = 0; q < 8; ++q) {
                    int code = (half * 8 + q) * 16 + l15;
                    int sw = (code & 7);
                    const char* ph0 = sH + code * 128 + (((kgrp    ) ^ sw) << 4);
                    const char* ph1 = sH + code * 128 + (((kgrp + 4) ^ sw) << 4);
                    const char* pl0 = sL + code * 128 + (((kgrp    ) ^ sw) << 4);
                    const char* pl1 = sL + code * 128 + (((kgrp + 4) ^ sw) << 4);
                    f16x8 bh_0 = *(const f16x8*)ph0, bh_1 = *(const f16x8*)ph1;
                    f16x8 bl_0 = *(const f16x8*)pl0, bl_1 = *(const f16x8*)pl1;
                    a1[q] = mfma32(rh0, bh_0, a1[q]);
                    a2[q] = mfma32(rl0, bh_0, a2[q]);
                    a2[q] = mfma32(rh0, bl_0, a2[q]);
                    a1[q] = mfma32(rh1, bh_1, a1[q]);
                    a2[q] = mfma32(rl1, bh_1, a2[q]);
                    a2[q] = mfma32(rh1, bl_1, a2[q]);
                }
#pragma unroll
                for (int q = 0; q < 8; ++q) {
                    int nf = half * 8 + q;
                    int code = nf * 16 + l15;
#pragma unroll
                    for (int j = 0; j < 4; ++j) {
                        float dot = fmaf(a2[q][j], (1.f / 4096.f), a1[q][j]);
                        float d = fmaf(dot, -2.f, cn[nf]);
                        bool better = (d < dmin[j]);
                        dmin[j] = better ? d : dmin[j];
                        imin[j] = better ? code : imin[j];
                    }
                }
            }

#pragma unroll
            for (int m = 1; m < 16; m <<= 1) {
#pragma unroll
                for (int j = 0; j < 4; ++j) {
                    float d2 = __shfl_xor(dmin[j], m);
                    int   i2 = __shfl_xor(imin[j], m);
                    bool better = (d2 < dmin[j]) || (d2 == dmin[j] && i2 < imin[j]);
                    dmin[j] = better ? d2 : dmin[j];
                    imin[j] = better ? i2 : imin[j];
                }
            }

            if (l15 == 0) {
#pragma unroll
                for (int j = 0; j < 4; ++j) {
                    size_t row = rowbase + t * 16 + kgrp * 4 + j;
                    idx_out[row * 4 + lvl] = (float)imin[j];
                }
            }

            int srcl = (l15 >> 2) << 4;
            int b0 = __shfl(imin[0], srcl);
            int b1 = __shfl(imin[1], srcl);
            int b2 = __shfl(imin[2], srcl);
            int b3 = __shfl(imin[3], srcl);
            int jj = l15 & 3;
            int bestRow = (jj & 2) ? ((jj & 1) ? b3 : b2) : ((jj & 1) ? b1 : b0);

            int sw = (bestRow & 7);
#pragma unroll
            for (int kf = 0; kf < 2; ++kf) {
                int slot = kgrp + kf * 4;
                f16x8 eh = *(const f16x8*)(sH + bestRow * 128 + ((slot ^ sw) << 4));
                f16x8 el = *(const f16x8*)(sL + bestRow * 128 + ((slot ^ sw) << 4));
#pragma unroll
                for (int i = 0; i < 8; ++i) {
                    float ev = fmaf((float)el[i], (1.f / 4096.f), (float)eh[i]);
                    float rn = rf[t][kf * 8 + i] - ev;
                    lsum += rn * rn;
                    rf[t][kf * 8 + i] = rn;
                }
            }
        }
    }

#pragma unroll
    for (int t = 0; t < 4; ++t) {
        size_t row = rowbase + t * 16 + l15;
        const float* zr = z + row * 64;
        short* xr = xqb + row * 64;
#pragma unroll
        for (int kf = 0; kf < 2; ++kf) {
            float4 v0 = *(const float4*)(zr + kf * 32 + d0);
            float4 v1 = *(const float4*)(zr + kf * 32 + d0 + 4);
            float vv[8] = {v0.x, v0.y, v0.z, v0.w, v1.x, v1.y, v1.z, v1.w};
            short ob[8];
#pragma unroll
            for (int i = 0; i < 8; ++i)
                ob[i] = f2bf(vv[i] - rf[t][kf * 8 + i]);
            *(s16x8*)(xr + kf * 32 + d0) = *(s16x8*)ob;
        }
    }

#pragma unroll
    for (int off = 32; off > 0; off >>= 1)
        lsum += __shfl_down(lsum, off);
    if (lane == 0) atomicAdd(loss1, lsum);
}

__global__ void finalize_loss(const float* __restrict__ loss1, float* __restrict__ rq)
{
    if (threadIdx.x == 0)
        rq[0] = 1.25f * loss1[0] / (4.0f * (float)NROW * 64.0f);
}

extern "C" void kernel_launch(void* const* d_in, const int* in_sizes, int n_in,
                              void* d_out, int out_size, void* d_ws, size_t ws_size,
                              hipStream_t stream)
{
    const float* ew0 = (const float*)d_in[0];
    const float* eb0 = (const float*)d_in[1];
    const float* ew1 = (const float*)d_in[2];
    const float* eb1 = (const float*)d_in[3];
    const float* ew2 = (const float*)d_in[4];
    const float* eb2 = (const float*)d_in[5];
    const float* dw0 = (const float*)d_in[6];
    const float* db0 = (const float*)d_in[7];
    const float* dw1 = (const float*)d_in[8];
    const float* db1 = (const float*)d_in[9];
    const float* dw2 = (const float*)d_in[10];
    const float* db2 = (const float*)d_in[11];
    const float* cb  = (const float*)d_in[12];
    const float* x   = (const float*)d_in[13];

    const size_t N = NROW;
    char* w = (char*)d_ws;
    _Float16* h1h = (_Float16*)w;                 w += N * 512 * 2;
    _Float16* h1l = (_Float16*)w;                 w += N * 512 * 2;
    _Float16* h2h = (_Float16*)w;                 w += N * 256 * 2;
    _Float16* h2l = (_Float16*)w;                 w += N * 256 * 2;
    float*    z   = (float*)w;                    w += N * 64 * 4;
    short*    xqb = (short*)w;                    w += N * 64 * 2;
    _Float16* we0h = (_Float16*)w;                w += 512 * 768 * 2;
    _Float16* we0l = (_Float16*)w;                w += 512 * 768 * 2;
    _Float16* we1h = (_Float16*)w;                w += 256 * 512 * 2;
    _Float16* we1l = (_Float16*)w;                w += 256 * 512 * 2;
    _Float16* we2h = (_Float16*)w;                w += 64 * 256 * 2;
    _Float16* we2l = (_Float16*)w;                w += 64 * 256 * 2;
    short*    wd0  = (short*)w;                   w += 256 * 64 * 2;
    short*    wd1  = (short*)w;                   w += 512 * 256 * 2;
    short*    wd2  = (short*)w;                   w += 768 * 512 * 2;
    float*    loss1 = (float*)w;                  w += 256;
    _Float16* cbh_g = (_Float16*)w;               w += 4 * 256 * 64 * 2;
    _Float16* cbl_g = (_Float16*)w;               w += 4 * 256 * 64 * 2;
    float*    cnorm_g = (float*)w;                w += 4 * 256 * 4;

    float* out  = (float*)d_out;                  // N*768
    float* rq   = out + N * 768;                  // 1
    float* idxf = rq + 1;                         // N*4

    _Float16* xh = (_Float16*)d_out;
    _Float16* xl = xh + N * 768;

    hipMemsetAsync(loss1, 0, sizeof(float), stream);

    dim3 blk(256);
    prep_x<<<dim3(2048), blk, 0, stream>>>(x, xh, xl);
    prep_cb<<<dim3(4), blk, 0, stream>>>(cb, cbh_g, cbl_g, cnorm_g);
    prep_w<true ><<<dim3(512/32, 768/32), blk, 0, stream>>>(ew0, we0h, we0l, 768, 512);
    prep_w<true ><<<dim3(256/32, 512/32), blk, 0, stream>>>(ew1, we1h, we1l, 512, 256);
    prep_w<true ><<<dim3( 64/32, 256/32), blk, 0, stream>>>(ew2, we2h, we2l, 256,  64);
    prep_w<false><<<dim3(256/32,  64/32), blk, 0, stream>>>(dw0, wd0, nullptr,  64, 256);
    prep_w<false><<<dim3(512/32, 256/32), blk, 0, stream>>>(dw1, wd1, nullptr, 256, 512);
    prep_w<false><<<dim3(768/32, 512/32), blk, 0, stream>>>(dw2, wd2, nullptr, 512, 768);

    // encoder: fp16-split MFMA; E0/E1 128x128 BK=32 (32KB LDS, 4 blk/CU),
    // E2 128x64 BK=64
    mm_mfma<_Float16, true, 1, 128, 128, 32, true ><<<dim3(4, N/128), blk, 0, stream>>>(
        xh, xl, we0h, we0l, eb0, h1h, h1l, (int)N, 512, 768);
    mm_mfma<_Float16, true, 1, 128, 128, 32, true ><<<dim3(2, N/128), blk, 0, stream>>>(
        h1h, h1l, we1h, we1l, eb1, h2h, h2l, (int)N, 256, 512);
    mm_mfma<_Float16, true, 0, 128, 64, 64, false><<<dim3(1, N/128), blk, 0, stream>>>(
        h2h, h2l, we2h, we2l, eb2, z, nullptr, (int)N, 64, 256);

    // MFMA residual quantization
    rq_mfma<<<dim3(N/256), blk, 0, stream>>>(z, cbh_g, cbl_g, cnorm_g, xqb, idxf, loss1);
    finalize_loss<<<dim3(1), dim3(64), 0, stream>>>(loss1, rq);

    // decoder: bf16 MFMA, 128x128 tiles BK=64 (32KB, 4 blk/CU), coalesced epi
    short* h2b = (short*)h2h;
    short* h1b = (short*)h1h;
    mm_mfma<short, false, 2, 128, 128, 64, true ><<<dim3(2, N/128), blk, 0, stream>>>(
        xqb, nullptr, wd0, nullptr, db0, h2b, nullptr, (int)N, 256, 64);
    mm_mfma<short, false, 2, 128, 128, 64, true ><<<dim3(4, N/128), blk, 0, stream>>>(
        h2b, nullptr, wd1, nullptr, db1, h1b, nullptr, (int)N, 512, 256);
    mm_mfma<short, false, 0, 128, 128, 64, false><<<dim3(6, N/128), blk, 0, stream>>>(
        h1b, nullptr, wd2, nullptr, db2, out, nullptr, (int)N, 768, 512);
}

// Round 12
// 1572.682 us; speedup vs baseline: 2.9662x; 2.9662x over previous
//
#include <hip/hip_runtime.h>
#include <hip/hip_bf16.h>
#include <float.h>
#include <type_traits>

#define NROW 131072

using f16x8 = __attribute__((ext_vector_type(8))) _Float16;
using f16x4 = __attribute__((ext_vector_type(4))) _Float16;
using s16x8 = __attribute__((ext_vector_type(8))) short;
using f32x4 = __attribute__((ext_vector_type(4))) float;

__device__ __forceinline__ f32x4 mfma32(f16x8 a, f16x8 b, f32x4 c) {
    return __builtin_amdgcn_mfma_f32_16x16x32_f16(a, b, c, 0, 0, 0);
}
__device__ __forceinline__ f32x4 mfma32(s16x8 a, s16x8 b, f32x4 c) {
    return __builtin_amdgcn_mfma_f32_16x16x32_bf16(a, b, c, 0, 0, 0);
}

__device__ __forceinline__ short f2bf(float f) {
    unsigned u = __builtin_bit_cast(unsigned, f);
    u += 0x7fffu + ((u >> 16) & 1u);
    return (short)(u >> 16);
}

__device__ __forceinline__ void gload16(const void* g, void* l) {
    __builtin_amdgcn_global_load_lds(
        (const __attribute__((address_space(1))) void*)g,
        (__attribute__((address_space(3))) void*)l, 16, 0, 0);
}

// ---------------------------------------------------------------------------
// MFMA GEMM v9 = r10's v7 (best measured: 1267us total) with ONE change:
// D1/D2 use 256x128 tiles (A-panel reuse x2; r9's failure at this shape was
// the write-amplification epilogue, fixed in r10 by coalesced stores).
// r11 lesson: 128x128-SPLIT at launch_bounds>=4 spills (needs ~160 VGPR,
// cap 128) -> scratch traffic x20. Keep SPLIT shapes at bound<=3.
//  - Single-buffered stage->sync->compute->sync (r7-proven best schedule).
//  - SPLIT rows: BK=64 -> 256B = 16 slots (hi 0-7, lo 8-15), phys slot =
//    logical ^ (row&15); bf16 rows 128B, 8 slots, ^(row&7). Inverse swizzle
//    on per-lane GLOBAL source, LDS dest linear (rule 21; 0 conflicts).
//  - Coalesced LDS-staged epilogue (r10-proven: exact HBM writes).
//  - Stage pointers precomputed once; XCD-chunked bijective remap.
// A:[M][K] ET row-major, Bt:[N][K]. OUT: 0=f32, 1=fp16 hi/lo split
// (lo pre-scaled 4096), 2=bf16. Waves fixed 2x2.
// ---------------------------------------------------------------------------
template<typename ET, bool SPLIT, int OUT, int BM, int BN, int BK, bool RELU>
__global__ __launch_bounds__(256,
    (SPLIT ? 2 :
     (((BM + BN) * BK * 2) <= 32768 ? 4 :
      (((BM + BN) * BK * 2) <= 49152 ? 3 : 2))))
void mm_mfma(
    const ET* __restrict__ Ah, const ET* __restrict__ Al,
    const ET* __restrict__ Bh, const ET* __restrict__ Bl,
    const float* __restrict__ bias,
    void* __restrict__ O0, void* __restrict__ O1,
    int M, int N, int K)
{
    constexpr int WTM = BM / 2, WTN = BN / 2;
    constexpr int MF = WTM / 16, NF = WTN / 16;
    constexpr int KS = BK / 32;
    constexpr int RB = SPLIT ? BK * 4 : BK * 2;   // row bytes
    constexpr int SLOTS = RB / 16;
    constexpr int SMASK = SLOTS - 1;
    constexpr int RPI = 1024 / RB;                // rows per staging inst
    constexpr int IA = BM * RB / 1024;
    constexpr int IB = BN * RB / 1024;
    constexpr int IT = IA + IB;
    constexpr int IPW = IT / 4;
    static_assert(IT % 4 == 0, "staging insts must split across 4 waves");
    using VT = typename std::conditional<std::is_same<ET, _Float16>::value,
                                         f16x8, s16x8>::type;

    __shared__ __align__(16) char smem[(BM + BN) * RB];

    const int tid  = threadIdx.x;
    const int lane = tid & 63;
    const int wave = tid >> 6;
    const int wm = wave >> 1, wn = wave & 1;

    // XCD-chunked bijective remap (all grids have nwg % 8 == 0)
    int gx = gridDim.x, nwg = gx * gridDim.y;
    int id = blockIdx.y * gx + blockIdx.x;
    int l  = (nwg & 7) ? id : ((id & 7) * (nwg >> 3) + (id >> 3));
    const int bm = (l / gx) * BM;
    const int bn = (l % gx) * BN;

    // ---- precompute staging pointers (register arrays, static indices)
    const int r_loc = lane / SLOTS;
    const int p     = lane % SLOTS;
    const char* gsrc[IPW];
    int ldst[IPW];
#pragma unroll
    for (int i = 0; i < IPW; ++i) {
        int inst = wave * IPW + i;
        bool isA = inst < IA;
        int li   = isA ? inst : inst - IA;
        int row  = li * RPI + r_loc;
        int g    = p ^ (row & SMASK);
        int grow = (isA ? bm : bn) + row;
        const ET* s; int col;
        if constexpr (SPLIT) {
            s   = (g < SLOTS / 2) ? (isA ? Ah : Bh) : (isA ? Al : Bl);
            col = (g & (SLOTS / 2 - 1)) * 8;
        } else {
            s   = isA ? Ah : Bh;
            col = g * 8;
        }
        gsrc[i] = (const char*)(s + (size_t)grow * K + col);
        ldst[i] = (isA ? 0 : BM * RB) + li * 1024;
    }

    char* sA = smem;
    char* sB = smem + BM * RB;

    f32x4 acc1[MF][NF];
    f32x4 acc2[SPLIT ? MF : 1][SPLIT ? NF : 1];
#pragma unroll
    for (int m = 0; m < MF; ++m)
#pragma unroll
        for (int n = 0; n < NF; ++n) {
            acc1[m][n] = f32x4{0.f, 0.f, 0.f, 0.f};
            if constexpr (SPLIT) acc2[m][n] = f32x4{0.f, 0.f, 0.f, 0.f};
        }

    const int kg  = lane >> 4;     // k-group 0..3
    const int l15 = lane & 15;

    for (int k0 = 0; k0 < K; k0 += BK) {
#pragma unroll
        for (int i = 0; i < IPW; ++i)
            gload16(gsrc[i] + (size_t)k0 * sizeof(ET), smem + ldst[i]);
        __syncthreads();
#pragma unroll
        for (int ks = 0; ks < KS; ++ks) {
            const int hslot = ks * 4 + kg;
            VT bh_[NF]; VT bl_[SPLIT ? NF : 1];
#pragma unroll
            for (int n = 0; n < NF; ++n) {
                int nr = wn * WTN + n * 16 + l15;
                bh_[n] = *(const VT*)(sB + nr * RB + ((hslot ^ (nr & SMASK)) << 4));
                if constexpr (SPLIT)
                    bl_[n] = *(const VT*)(sB + nr * RB +
                              (((SLOTS / 2 + hslot) ^ (nr & SMASK)) << 4));
            }
#pragma unroll
            for (int m = 0; m < MF; ++m) {
                int mr = wm * WTM + m * 16 + l15;
                VT a_h = *(const VT*)(sA + mr * RB + ((hslot ^ (mr & SMASK)) << 4));
                VT a_l;
                if constexpr (SPLIT)
                    a_l = *(const VT*)(sA + mr * RB +
                          (((SLOTS / 2 + hslot) ^ (mr & SMASK)) << 4));
#pragma unroll
                for (int n = 0; n < NF; ++n) {
                    acc1[m][n] = mfma32(a_h, bh_[n], acc1[m][n]);
                    if constexpr (SPLIT) {
                        acc2[m][n] = mfma32(a_l, bh_[n], acc2[m][n]);
                        acc2[m][n] = mfma32(a_h, bl_[n], acc2[m][n]);
                    }
                }
            }
        }
        __syncthreads();
    }

    // ---------------- epilogue: LDS-staged coalesced stores ----------------
    constexpr int OELT = (OUT == 0) ? 4 : 2;      // output element bytes
    constexpr int ROWB = WTN * OELT;              // logical row bytes
    constexpr int RSTR = ROWB + 16;               // padded stride
    constexpr int NRG  = (OUT == 1) ? 2 : 1;
    constexpr int SCR  = 16 * RSTR * NRG;         // per-wave scratch bytes
    char* wscr = smem + wave * SCR;
    const int colb = bn + wn * WTN;

#pragma unroll
    for (int m = 0; m < MF; ++m) {
#pragma unroll
        for (int n = 0; n < NF; ++n) {
            int cl = n * 16 + l15;
            float bv = bias[colb + cl];
            f32x4 v = acc1[m][n];
            if constexpr (SPLIT) {
                f32x4 v2 = acc2[m][n];
#pragma unroll
                for (int r = 0; r < 4; ++r) v[r] += v2[r] * (1.0f / 4096.0f);
            }
#pragma unroll
            for (int r = 0; r < 4; ++r) {
                float f = v[r] + bv;
                if constexpr (RELU) f = fmaxf(f, 0.f);
                int lr = kg * 4 + r;
                if constexpr (OUT == 0) {
                    *(float*)(wscr + lr * RSTR + cl * 4) = f;
                } else if constexpr (OUT == 1) {
                    _Float16 hi = (_Float16)f;
                    _Float16 lo = (_Float16)((f - (float)hi) * 4096.f);
                    *(_Float16*)(wscr + lr * RSTR + cl * 2) = hi;
                    *(_Float16*)(wscr + 16 * RSTR + lr * RSTR + cl * 2) = lo;
                } else {
                    *(short*)(wscr + lr * RSTR + cl * 2) = f2bf(f);
                }
            }
        }
        asm volatile("s_waitcnt lgkmcnt(0)" ::: "memory");
        __builtin_amdgcn_sched_barrier(0);

        constexpr int LPR = ROWB / 16;
        constexpr int RPT = 64 / LPR;
        const int rr = lane / LPR;
        const int jj = lane % LPR;
#pragma unroll
        for (int g = 0; g < 16 / RPT; ++g) {
            int lr = g * RPT + rr;
            size_t grow = (size_t)(bm + wm * WTM + m * 16 + lr);
            if constexpr (OUT == 0) {
                float4 vv = *(const float4*)(wscr + lr * RSTR + jj * 16);
                *(float4*)((float*)O0 + grow * N + colb + jj * 4) = vv;
            } else if constexpr (OUT == 1) {
                f16x8 hv = *(const f16x8*)(wscr + lr * RSTR + jj * 16);
                f16x8 lv = *(const f16x8*)(wscr + 16 * RSTR + lr * RSTR + jj * 16);
                *(f16x8*)((_Float16*)O0 + grow * N + colb + jj * 8) = hv;
                *(f16x8*)((_Float16*)O1 + grow * N + colb + jj * 8) = lv;
            } else {
                s16x8 vv = *(const s16x8*)(wscr + lr * RSTR + jj * 16);
                *(s16x8*)((short*)O0 + grow * N + colb + jj * 8) = vv;
            }
        }
        asm volatile("s_waitcnt lgkmcnt(0)" ::: "memory");
        __builtin_amdgcn_sched_barrier(0);
    }
}

// ---------------------------------------------------------------------------
// x (f32) -> xh, xl (fp16, lo pre-scaled by 4096)
// ---------------------------------------------------------------------------
__global__ __launch_bounds__(256) void prep_x(
    const float* __restrict__ x, _Float16* __restrict__ xh, _Float16* __restrict__ xl)
{
    const size_t total = (size_t)NROW * 768 / 4;
    for (size_t i = (size_t)blockIdx.x * 256 + threadIdx.x; i < total;
         i += (size_t)gridDim.x * 256) {
        float4 v = ((const float4*)x)[i];
        f16x4 h, ll;
        h[0] = (_Float16)v.x; h[1] = (_Float16)v.y;
        h[2] = (_Float16)v.z; h[3] = (_Float16)v.w;
        ll[0] = (_Float16)((v.x - (float)h[0]) * 4096.f);
        ll[1] = (_Float16)((v.y - (float)h[1]) * 4096.f);
        ll[2] = (_Float16)((v.z - (float)h[2]) * 4096.f);
        ll[3] = (_Float16)((v.w - (float)h[3]) * 4096.f);
        ((f16x4*)xh)[i] = h;
        ((f16x4*)xl)[i] = ll;
    }
}

// ---------------------------------------------------------------------------
// W [K][N] f32 -> transposed Th/Tl [N][K] (fp16 split or bf16)
// ---------------------------------------------------------------------------
template<bool SPLIT>
__global__ __launch_bounds__(256) void prep_w(
    const float* __restrict__ W, void* __restrict__ Th, void* __restrict__ Tl,
    int K, int N)
{
    __shared__ float t[32][33];
    const int bn = blockIdx.x * 32, bk = blockIdx.y * 32;
    const int lx = threadIdx.x & 31, ly = threadIdx.x >> 5;
#pragma unroll
    for (int i = 0; i < 32; i += 8)
        t[ly + i][lx] = W[(size_t)(bk + ly + i) * N + bn + lx];
    __syncthreads();
#pragma unroll
    for (int i = 0; i < 32; i += 8) {
        float v = t[lx][ly + i];
        size_t o = (size_t)(bn + ly + i) * K + bk + lx;
        if constexpr (SPLIT) {
            _Float16 hi = (_Float16)v;
            _Float16 lo = (_Float16)((v - (float)hi) * 4096.f);
            ((_Float16*)Th)[o] = hi;
            ((_Float16*)Tl)[o] = lo;
        } else {
            ((short*)Th)[o] = f2bf(v);
        }
    }
}

// ---------------------------------------------------------------------------
// Codebook prep: f32 [4][256][64] -> fp16 hi/lo [4][256][64] PRE-SWIZZLED
// (slot s of code c holds dims (s ^ (c&7))*8 .. +8) + f32 cnorm [4][256].
// ---------------------------------------------------------------------------
__global__ __launch_bounds__(256) void prep_cb(
    const float* __restrict__ cb, _Float16* __restrict__ ch,
    _Float16* __restrict__ cl, float* __restrict__ cn)
{
    const int lvl = blockIdx.x;
    const int code = threadIdx.x;
    const float* src = cb + ((size_t)lvl * 256 + code) * 64;
    _Float16* dh = ch + ((size_t)lvl * 256 + code) * 64;
    _Float16* dl = cl + ((size_t)lvl * 256 + code) * 64;
    float s = 0.f;
#pragma unroll
    for (int d = 0; d < 64; ++d) s += src[d] * src[d];
    cn[lvl * 256 + code] = s;
#pragma unroll
    for (int slot = 0; slot < 8; ++slot) {
        int ss = slot ^ (code & 7);
#pragma unroll
        for (int i = 0; i < 8; ++i) {
            float v = src[ss * 8 + i];
            _Float16 h = (_Float16)v;
            dh[slot * 8 + i] = h;
            dl[slot * 8 + i] = (_Float16)((v - (float)h) * 4096.f);
        }
    }
}

// ---------------------------------------------------------------------------
// MFMA residual quantizer (unchanged — measured off top-5).
// ---------------------------------------------------------------------------
__global__ __launch_bounds__(256, 2) void rq_mfma(
    const float* __restrict__ z,
    const _Float16* __restrict__ cbh_g, const _Float16* __restrict__ cbl_g,
    const float* __restrict__ cnorm_g,
    short* __restrict__ xqb, float* __restrict__ idx_out,
    float* __restrict__ loss1)
{
    __shared__ __align__(16) char sH[32768];
    __shared__ __align__(16) char sL[32768];
    __shared__ __align__(16) float sCN[256];

    const int tid  = threadIdx.x;
    const int lane = tid & 63;
    const int wave = tid >> 6;
    const int l15  = lane & 15;
    const int kgrp = lane >> 4;
    const int d0   = kgrp * 8;

    const size_t rowbase = (size_t)blockIdx.x * 256 + wave * 64;

    float rf[4][16];
#pragma unroll
    for (int t = 0; t < 4; ++t) {
        const float* zr = z + (rowbase + t * 16 + l15) * 64;
#pragma unroll
        for (int kf = 0; kf < 2; ++kf) {
            float4 v0 = *(const float4*)(zr + kf * 32 + d0);
            float4 v1 = *(const float4*)(zr + kf * 32 + d0 + 4);
            rf[t][kf * 8 + 0] = v0.x; rf[t][kf * 8 + 1] = v0.y;
            rf[t][kf * 8 + 2] = v0.z; rf[t][kf * 8 + 3] = v0.w;
            rf[t][kf * 8 + 4] = v1.x; rf[t][kf * 8 + 5] = v1.y;
            rf[t][kf * 8 + 6] = v1.z; rf[t][kf * 8 + 7] = v1.w;
        }
    }

    float lsum = 0.f;

    for (int lvl = 0; lvl < 4; ++lvl) {
        __syncthreads();
        {
            const char* gh = (const char*)(cbh_g + (size_t)lvl * 16384);
            const char* gl = (const char*)(cbl_g + (size_t)lvl * 16384);
            const char* gc = (const char*)(cnorm_g + lvl * 256);
            for (int i = wave; i < 65; i += 4) {
                if (i < 32)      gload16(gh + (size_t)i * 1024 + lane * 16, sH + i * 1024);
                else if (i < 64) gload16(gl + (size_t)(i - 32) * 1024 + lane * 16, sL + (i - 32) * 1024);
                else             gload16(gc + lane * 16, (char*)sCN);
            }
        }
        __syncthreads();

        float cn[16];
#pragma unroll
        for (int nf = 0; nf < 16; ++nf) cn[nf] = sCN[nf * 16 + l15];

        for (int t = 0; t < 4; ++t) {
            f16x8 rh0, rh1, rl0, rl1;
#pragma unroll
            for (int i = 0; i < 8; ++i) {
                _Float16 h = (_Float16)rf[t][i];
                rh0[i] = h;
                rl0[i] = (_Float16)((rf[t][i] - (float)h) * 4096.f);
                _Float16 h1 = (_Float16)rf[t][8 + i];
                rh1[i] = h1;
                rl1[i] = (_Float16)((rf[t][8 + i] - (float)h1) * 4096.f);
            }

            float dmin[4]; int imin[4];
#pragma unroll
            for (int j = 0; j < 4; ++j) { dmin[j] = FLT_MAX; imin[j] = 0; }

#pragma unroll
            for (int half = 0; half < 2; ++half) {
                f32x4 a1[8], a2[8];
#pragma unroll
                for (int q = 0; q < 8; ++q) {
                    a1[q] = f32x4{0.f, 0.f, 0.f, 0.f};
                    a2[q] = f32x4{0.f, 0.f, 0.f, 0.f};
                }
#pragma unroll
                for (int q = 0; q < 8; ++q) {
                    int code = (half * 8 + q) * 16 + l15;
                    int sw = (code & 7);
                    const char* ph0 = sH + code * 128 + (((kgrp    ) ^ sw) << 4);
                    const char* ph1 = sH + code * 128 + (((kgrp + 4) ^ sw) << 4);
                    const char* pl0 = sL + code * 128 + (((kgrp    ) ^ sw) << 4);
                    const char* pl1 = sL + code * 128 + (((kgrp + 4) ^ sw) << 4);
                    f16x8 bh_0 = *(const f16x8*)ph0, bh_1 = *(const f16x8*)ph1;
                    f16x8 bl_0 = *(const f16x8*)pl0, bl_1 = *(const f16x8*)pl1;
                    a1[q] = mfma32(rh0, bh_0, a1[q]);
                    a2[q] = mfma32(rl0, bh_0, a2[q]);
                    a2[q] = mfma32(rh0, bl_0, a2[q]);
                    a1[q] = mfma32(rh1, bh_1, a1[q]);
                    a2[q] = mfma32(rl1, bh_1, a2[q]);
                    a2[q] = mfma32(rh1, bl_1, a2[q]);
                }
#pragma unroll
                for (int q = 0; q < 8; ++q) {
                    int nf = half * 8 + q;
                    int code = nf * 16 + l15;
#pragma unroll
                    for (int j = 0; j < 4; ++j) {
                        float dot = fmaf(a2[q][j], (1.f / 4096.f), a1[q][j]);
                        float d = fmaf(dot, -2.f, cn[nf]);
                        bool better = (d < dmin[j]);
                        dmin[j] = better ? d : dmin[j];
                        imin[j] = better ? code : imin[j];
                    }
                }
            }

#pragma unroll
            for (int m = 1; m < 16; m <<= 1) {
#pragma unroll
                for (int j = 0; j < 4; ++j) {
                    float d2 = __shfl_xor(dmin[j], m);
                    int   i2 = __shfl_xor(imin[j], m);
                    bool better = (d2 < dmin[j]) || (d2 == dmin[j] && i2 < imin[j]);
                    dmin[j] = better ? d2 : dmin[j];
                    imin[j] = better ? i2 : imin[j];
                }
            }

            if (l15 == 0) {
#pragma unroll
                for (int j = 0; j < 4; ++j) {
                    size_t row = rowbase + t * 16 + kgrp * 4 + j;
                    idx_out[row * 4 + lvl] = (float)imin[j];
                }
            }

            int srcl = (l15 >> 2) << 4;
            int b0 = __shfl(imin[0], srcl);
            int b1 = __shfl(imin[1], srcl);
            int b2 = __shfl(imin[2], srcl);
            int b3 = __shfl(imin[3], srcl);
            int jj = l15 & 3;
            int bestRow = (jj & 2) ? ((jj & 1) ? b3 : b2) : ((jj & 1) ? b1 : b0);

            int sw = (bestRow & 7);
#pragma unroll
            for (int kf = 0; kf < 2; ++kf) {
                int slot = kgrp + kf * 4;
                f16x8 eh = *(const f16x8*)(sH + bestRow * 128 + ((slot ^ sw) << 4));
                f16x8 el = *(const f16x8*)(sL + bestRow * 128 + ((slot ^ sw) << 4));
#pragma unroll
                for (int i = 0; i < 8; ++i) {
                    float ev = fmaf((float)el[i], (1.f / 4096.f), (float)eh[i]);
                    float rn = rf[t][kf * 8 + i] - ev;
                    lsum += rn * rn;
                    rf[t][kf * 8 + i] = rn;
                }
            }
        }
    }

#pragma unroll
    for (int t = 0; t < 4; ++t) {
        size_t row = rowbase + t * 16 + l15;
        const float* zr = z + row * 64;
        short* xr = xqb + row * 64;
#pragma unroll
        for (int kf = 0; kf < 2; ++kf) {
            float4 v0 = *(const float4*)(zr + kf * 32 + d0);
            float4 v1 = *(const float4*)(zr + kf * 32 + d0 + 4);
            float vv[8] = {v0.x, v0.y, v0.z, v0.w, v1.x, v1.y, v1.z, v1.w};
            short ob[8];
#pragma unroll
            for (int i = 0; i < 8; ++i)
                ob[i] = f2bf(vv[i] - rf[t][kf * 8 + i]);
            *(s16x8*)(xr + kf * 32 + d0) = *(s16x8*)ob;
        }
    }

#pragma unroll
    for (int off = 32; off > 0; off >>= 1)
        lsum += __shfl_down(lsum, off);
    if (lane == 0) atomicAdd(loss1, lsum);
}

__global__ void finalize_loss(const float* __restrict__ loss1, float* __restrict__ rq)
{
    if (threadIdx.x == 0)
        rq[0] = 1.25f * loss1[0] / (4.0f * (float)NROW * 64.0f);
}

extern "C" void kernel_launch(void* const* d_in, const int* in_sizes, int n_in,
                              void* d_out, int out_size, void* d_ws, size_t ws_size,
                              hipStream_t stream)
{
    const float* ew0 = (const float*)d_in[0];
    const float* eb0 = (const float*)d_in[1];
    const float* ew1 = (const float*)d_in[2];
    const float* eb1 = (const float*)d_in[3];
    const float* ew2 = (const float*)d_in[4];
    const float* eb2 = (const float*)d_in[5];
    const float* dw0 = (const float*)d_in[6];
    const float* db0 = (const float*)d_in[7];
    const float* dw1 = (const float*)d_in[8];
    const float* db1 = (const float*)d_in[9];
    const float* dw2 = (const float*)d_in[10];
    const float* db2 = (const float*)d_in[11];
    const float* cb  = (const float*)d_in[12];
    const float* x   = (const float*)d_in[13];

    const size_t N = NROW;
    char* w = (char*)d_ws;
    _Float16* h1h = (_Float16*)w;                 w += N * 512 * 2;
    _Float16* h1l = (_Float16*)w;                 w += N * 512 * 2;
    _Float16* h2h = (_Float16*)w;                 w += N * 256 * 2;
    _Float16* h2l = (_Float16*)w;                 w += N * 256 * 2;
    float*    z   = (float*)w;                    w += N * 64 * 4;
    short*    xqb = (short*)w;                    w += N * 64 * 2;
    _Float16* we0h = (_Float16*)w;                w += 512 * 768 * 2;
    _Float16* we0l = (_Float16*)w;                w += 512 * 768 * 2;
    _Float16* we1h = (_Float16*)w;                w += 256 * 512 * 2;
    _Float16* we1l = (_Float16*)w;                w += 256 * 512 * 2;
    _Float16* we2h = (_Float16*)w;                w += 64 * 256 * 2;
    _Float16* we2l = (_Float16*)w;                w += 64 * 256 * 2;
    short*    wd0  = (short*)w;                   w += 256 * 64 * 2;
    short*    wd1  = (short*)w;                   w += 512 * 256 * 2;
    short*    wd2  = (short*)w;                   w += 768 * 512 * 2;
    float*    loss1 = (float*)w;                  w += 256;
    _Float16* cbh_g = (_Float16*)w;               w += 4 * 256 * 64 * 2;
    _Float16* cbl_g = (_Float16*)w;               w += 4 * 256 * 64 * 2;
    float*    cnorm_g = (float*)w;                w += 4 * 256 * 4;

    float* out  = (float*)d_out;                  // N*768
    float* rq   = out + N * 768;                  // 1
    float* idxf = rq + 1;                         // N*4

    _Float16* xh = (_Float16*)d_out;
    _Float16* xl = xh + N * 768;

    hipMemsetAsync(loss1, 0, sizeof(float), stream);

    dim3 blk(256);
    prep_x<<<dim3(2048), blk, 0, stream>>>(x, xh, xl);
    prep_cb<<<dim3(4), blk, 0, stream>>>(cb, cbh_g, cbl_g, cnorm_g);
    prep_w<true ><<<dim3(512/32, 768/32), blk, 0, stream>>>(ew0, we0h, we0l, 768, 512);
    prep_w<true ><<<dim3(256/32, 512/32), blk, 0, stream>>>(ew1, we1h, we1l, 512, 256);
    prep_w<true ><<<dim3( 64/32, 256/32), blk, 0, stream>>>(ew2, we2h, we2l, 256,  64);
    prep_w<false><<<dim3(256/32,  64/32), blk, 0, stream>>>(dw0, wd0, nullptr,  64, 256);
    prep_w<false><<<dim3(512/32, 256/32), blk, 0, stream>>>(dw1, wd1, nullptr, 256, 512);
    prep_w<false><<<dim3(768/32, 512/32), blk, 0, stream>>>(dw2, wd2, nullptr, 512, 768);

    // encoder: fp16-split MFMA, BK=64 (r10-proven); E0/E1 128x128, E2 128x64
    mm_mfma<_Float16, true, 1, 128, 128, 64, true ><<<dim3(4, N/128), blk, 0, stream>>>(
        xh, xl, we0h, we0l, eb0, h1h, h1l, (int)N, 512, 768);
    mm_mfma<_Float16, true, 1, 128, 128, 64, true ><<<dim3(2, N/128), blk, 0, stream>>>(
        h1h, h1l, we1h, we1l, eb1, h2h, h2l, (int)N, 256, 512);
    mm_mfma<_Float16, true, 0, 128, 64, 64, false><<<dim3(1, N/128), blk, 0, stream>>>(
        h2h, h2l, we2h, we2l, eb2, z, nullptr, (int)N, 64, 256);

    // MFMA residual quantization
    rq_mfma<<<dim3(N/256), blk, 0, stream>>>(z, cbh_g, cbl_g, cnorm_g, xqb, idxf, loss1);
    finalize_loss<<<dim3(1), dim3(64), 0, stream>>>(loss1, rq);

    // decoder: bf16 MFMA; D0 128x128, D1/D2 256x128 (A-reuse x2, 3 blk/CU)
    short* h2b = (short*)h2h;
    short* h1b = (short*)h1h;
    mm_mfma<short, false, 2, 128, 128, 64, true ><<<dim3(2, N/128), blk, 0, stream>>>(
        xqb, nullptr, wd0, nullptr, db0, h2b, nullptr, (int)N, 256, 64);
    mm_mfma<short, false, 2, 256, 128, 64, true ><<<dim3(4, N/256), blk, 0, stream>>>(
        h2b, nullptr, wd1, nullptr, db1, h1b, nullptr, (int)N, 512, 256);
    mm_mfma<short, false, 0, 256, 128, 64, false><<<dim3(6, N/256), blk, 0, stream>>>(
        h1b, nullptr, wd2, nullptr, db2, out, nullptr, (int)N, 768, 512);
}

// Round 13
// 1266.532 us; speedup vs baseline: 3.6832x; 1.2417x over previous
//
#include <hip/hip_runtime.h>
#include <hip/hip_bf16.h>
#include <float.h>
#include <type_traits>

#define NROW 131072

using f16x8 = __attribute__((ext_vector_type(8))) _Float16;
using f16x4 = __attribute__((ext_vector_type(4))) _Float16;
using s16x8 = __attribute__((ext_vector_type(8))) short;
using f32x4 = __attribute__((ext_vector_type(4))) float;

__device__ __forceinline__ f32x4 mfma32(f16x8 a, f16x8 b, f32x4 c) {
    return __builtin_amdgcn_mfma_f32_16x16x32_f16(a, b, c, 0, 0, 0);
}
__device__ __forceinline__ f32x4 mfma32(s16x8 a, s16x8 b, f32x4 c) {
    return __builtin_amdgcn_mfma_f32_16x16x32_bf16(a, b, c, 0, 0, 0);
}

__device__ __forceinline__ short f2bf(float f) {
    unsigned u = __builtin_bit_cast(unsigned, f);
    u += 0x7fffu + ((u >> 16) & 1u);
    return (short)(u >> 16);
}

__device__ __forceinline__ void gload16(const void* g, void* l) {
    __builtin_amdgcn_global_load_lds(
        (const __attribute__((address_space(1))) void*)g,
        (__attribute__((address_space(3))) void*)l, 16, 0, 0);
}

// ---------------------------------------------------------------------------
// MFMA GEMM v10 == r10's v7 verbatim (measured best: 1267us total).
// Session lessons encoded here:
//  - Single-buffered stage->sync->compute->sync is the best schedule found;
//    2-phase dbuf at source level regressed (compiler re-serializes, r8).
//  - SPLIT 128x128 BK=64 (64KB LDS, 2 blk/CU) is E0/E1's best shape;
//    BK=32+bound4 spills (r11), 128x64 is slower (r7).
//  - bf16 decoder: 128x128 BK=64 bound 4 (VGPR ~104 < 128 cap, no spill).
//    256-row tiles spill at bound 3 (need ~190 unified regs; r9+r12).
//  - SPLIT rows: 256B = 16 slots (hi 0-7, lo 8-15), phys = logical^(row&15);
//    bf16 rows 128B, 8 slots, ^(row&7). Inverse swizzle on per-lane GLOBAL
//    source, LDS dest linear (rule 21; 0 bank conflicts).
//  - Coalesced LDS-staged epilogue (exact HBM writes; r10).
//  - Stage pointers precomputed once; XCD-chunked bijective remap.
// A:[M][K] ET row-major, Bt:[N][K]. OUT: 0=f32, 1=fp16 hi/lo split
// (lo pre-scaled 4096), 2=bf16. Waves fixed 2x2.
// ---------------------------------------------------------------------------
template<typename ET, bool SPLIT, int OUT, int BM, int BN, int BK, bool RELU>
__global__ __launch_bounds__(256,
    ((BM + BN) * (SPLIT ? BK * 4 : BK * 2)) <= 32768 ? 4 :
    (((BM + BN) * (SPLIT ? BK * 4 : BK * 2)) <= 49152 ? 3 : 2))
void mm_mfma(
    const ET* __restrict__ Ah, const ET* __restrict__ Al,
    const ET* __restrict__ Bh, const ET* __restrict__ Bl,
    const float* __restrict__ bias,
    void* __restrict__ O0, void* __restrict__ O1,
    int M, int N, int K)
{
    constexpr int WTM = BM / 2, WTN = BN / 2;
    constexpr int MF = WTM / 16, NF = WTN / 16;
    constexpr int KS = BK / 32;
    constexpr int RB = SPLIT ? BK * 4 : BK * 2;   // row bytes
    constexpr int SLOTS = RB / 16;
    constexpr int SMASK = SLOTS - 1;
    constexpr int RPI = 1024 / RB;                // rows per staging inst
    constexpr int IA = BM * RB / 1024;
    constexpr int IB = BN * RB / 1024;
    constexpr int IT = IA + IB;
    constexpr int IPW = IT / 4;
    static_assert(IT % 4 == 0, "staging insts must split across 4 waves");
    using VT = typename std::conditional<std::is_same<ET, _Float16>::value,
                                         f16x8, s16x8>::type;

    __shared__ __align__(16) char smem[(BM + BN) * RB];

    const int tid  = threadIdx.x;
    const int lane = tid & 63;
    const int wave = tid >> 6;
    const int wm = wave >> 1, wn = wave & 1;

    // XCD-chunked bijective remap (all grids have nwg % 8 == 0)
    int gx = gridDim.x, nwg = gx * gridDim.y;
    int id = blockIdx.y * gx + blockIdx.x;
    int l  = (nwg & 7) ? id : ((id & 7) * (nwg >> 3) + (id >> 3));
    const int bm = (l / gx) * BM;
    const int bn = (l % gx) * BN;

    // ---- precompute staging pointers (register arrays, static indices)
    const int r_loc = lane / SLOTS;
    const int p     = lane % SLOTS;
    const char* gsrc[IPW];
    int ldst[IPW];
#pragma unroll
    for (int i = 0; i < IPW; ++i) {
        int inst = wave * IPW + i;
        bool isA = inst < IA;
        int li   = isA ? inst : inst - IA;
        int row  = li * RPI + r_loc;
        int g    = p ^ (row & SMASK);
        int grow = (isA ? bm : bn) + row;
        const ET* s; int col;
        if constexpr (SPLIT) {
            s   = (g < SLOTS / 2) ? (isA ? Ah : Bh) : (isA ? Al : Bl);
            col = (g & (SLOTS / 2 - 1)) * 8;
        } else {
            s   = isA ? Ah : Bh;
            col = g * 8;
        }
        gsrc[i] = (const char*)(s + (size_t)grow * K + col);
        ldst[i] = (isA ? 0 : BM * RB) + li * 1024;
    }

    char* sA = smem;
    char* sB = smem + BM * RB;

    f32x4 acc1[MF][NF];
    f32x4 acc2[SPLIT ? MF : 1][SPLIT ? NF : 1];
#pragma unroll
    for (int m = 0; m < MF; ++m)
#pragma unroll
        for (int n = 0; n < NF; ++n) {
            acc1[m][n] = f32x4{0.f, 0.f, 0.f, 0.f};
            if constexpr (SPLIT) acc2[m][n] = f32x4{0.f, 0.f, 0.f, 0.f};
        }

    const int kg  = lane >> 4;     // k-group 0..3
    const int l15 = lane & 15;

    for (int k0 = 0; k0 < K; k0 += BK) {
#pragma unroll
        for (int i = 0; i < IPW; ++i)
            gload16(gsrc[i] + (size_t)k0 * sizeof(ET), smem + ldst[i]);
        __syncthreads();
#pragma unroll
        for (int ks = 0; ks < KS; ++ks) {
            const int hslot = ks * 4 + kg;
            VT bh_[NF]; VT bl_[SPLIT ? NF : 1];
#pragma unroll
            for (int n = 0; n < NF; ++n) {
                int nr = wn * WTN + n * 16 + l15;
                bh_[n] = *(const VT*)(sB + nr * RB + ((hslot ^ (nr & SMASK)) << 4));
                if constexpr (SPLIT)
                    bl_[n] = *(const VT*)(sB + nr * RB +
                              (((SLOTS / 2 + hslot) ^ (nr & SMASK)) << 4));
            }
#pragma unroll
            for (int m = 0; m < MF; ++m) {
                int mr = wm * WTM + m * 16 + l15;
                VT a_h = *(const VT*)(sA + mr * RB + ((hslot ^ (mr & SMASK)) << 4));
                VT a_l;
                if constexpr (SPLIT)
                    a_l = *(const VT*)(sA + mr * RB +
                          (((SLOTS / 2 + hslot) ^ (mr & SMASK)) << 4));
#pragma unroll
                for (int n = 0; n < NF; ++n) {
                    acc1[m][n] = mfma32(a_h, bh_[n], acc1[m][n]);
                    if constexpr (SPLIT) {
                        acc2[m][n] = mfma32(a_l, bh_[n], acc2[m][n]);
                        acc2[m][n] = mfma32(a_h, bl_[n], acc2[m][n]);
                    }
                }
            }
        }
        __syncthreads();
    }

    // ---------------- epilogue: LDS-staged coalesced stores ----------------
    constexpr int OELT = (OUT == 0) ? 4 : 2;      // output element bytes
    constexpr int ROWB = WTN * OELT;              // logical row bytes
    constexpr int RSTR = ROWB + 16;               // padded stride
    constexpr int NRG  = (OUT == 1) ? 2 : 1;
    constexpr int SCR  = 16 * RSTR * NRG;         // per-wave scratch bytes
    char* wscr = smem + wave * SCR;
    const int colb = bn + wn * WTN;

#pragma unroll
    for (int m = 0; m < MF; ++m) {
#pragma unroll
        for (int n = 0; n < NF; ++n) {
            int cl = n * 16 + l15;
            float bv = bias[colb + cl];
            f32x4 v = acc1[m][n];
            if constexpr (SPLIT) {
                f32x4 v2 = acc2[m][n];
#pragma unroll
                for (int r = 0; r < 4; ++r) v[r] += v2[r] * (1.0f / 4096.0f);
            }
#pragma unroll
            for (int r = 0; r < 4; ++r) {
                float f = v[r] + bv;
                if constexpr (RELU) f = fmaxf(f, 0.f);
                int lr = kg * 4 + r;
                if constexpr (OUT == 0) {
                    *(float*)(wscr + lr * RSTR + cl * 4) = f;
                } else if constexpr (OUT == 1) {
                    _Float16 hi = (_Float16)f;
                    _Float16 lo = (_Float16)((f - (float)hi) * 4096.f);
                    *(_Float16*)(wscr + lr * RSTR + cl * 2) = hi;
                    *(_Float16*)(wscr + 16 * RSTR + lr * RSTR + cl * 2) = lo;
                } else {
                    *(short*)(wscr + lr * RSTR + cl * 2) = f2bf(f);
                }
            }
        }
        asm volatile("s_waitcnt lgkmcnt(0)" ::: "memory");
        __builtin_amdgcn_sched_barrier(0);

        constexpr int LPR = ROWB / 16;
        constexpr int RPT = 64 / LPR;
        const int rr = lane / LPR;
        const int jj = lane % LPR;
#pragma unroll
        for (int g = 0; g < 16 / RPT; ++g) {
            int lr = g * RPT + rr;
            size_t grow = (size_t)(bm + wm * WTM + m * 16 + lr);
            if constexpr (OUT == 0) {
                float4 vv = *(const float4*)(wscr + lr * RSTR + jj * 16);
                *(float4*)((float*)O0 + grow * N + colb + jj * 4) = vv;
            } else if constexpr (OUT == 1) {
                f16x8 hv = *(const f16x8*)(wscr + lr * RSTR + jj * 16);
                f16x8 lv = *(const f16x8*)(wscr + 16 * RSTR + lr * RSTR + jj * 16);
                *(f16x8*)((_Float16*)O0 + grow * N + colb + jj * 8) = hv;
                *(f16x8*)((_Float16*)O1 + grow * N + colb + jj * 8) = lv;
            } else {
                s16x8 vv = *(const s16x8*)(wscr + lr * RSTR + jj * 16);
                *(s16x8*)((short*)O0 + grow * N + colb + jj * 8) = vv;
            }
        }
        asm volatile("s_waitcnt lgkmcnt(0)" ::: "memory");
        __builtin_amdgcn_sched_barrier(0);
    }
}

// ---------------------------------------------------------------------------
// x (f32) -> xh, xl (fp16, lo pre-scaled by 4096)
// ---------------------------------------------------------------------------
__global__ __launch_bounds__(256) void prep_x(
    const float* __restrict__ x, _Float16* __restrict__ xh, _Float16* __restrict__ xl)
{
    const size_t total = (size_t)NROW * 768 / 4;
    for (size_t i = (size_t)blockIdx.x * 256 + threadIdx.x; i < total;
         i += (size_t)gridDim.x * 256) {
        float4 v = ((const float4*)x)[i];
        f16x4 h, ll;
        h[0] = (_Float16)v.x; h[1] = (_Float16)v.y;
        h[2] = (_Float16)v.z; h[3] = (_Float16)v.w;
        ll[0] = (_Float16)((v.x - (float)h[0]) * 4096.f);
        ll[1] = (_Float16)((v.y - (float)h[1]) * 4096.f);
        ll[2] = (_Float16)((v.z - (float)h[2]) * 4096.f);
        ll[3] = (_Float16)((v.w - (float)h[3]) * 4096.f);
        ((f16x4*)xh)[i] = h;
        ((f16x4*)xl)[i] = ll;
    }
}

// ---------------------------------------------------------------------------
// W [K][N] f32 -> transposed Th/Tl [N][K] (fp16 split or bf16)
// ---------------------------------------------------------------------------
template<bool SPLIT>
__global__ __launch_bounds__(256) void prep_w(
    const float* __restrict__ W, void* __restrict__ Th, void* __restrict__ Tl,
    int K, int N)
{
    __shared__ float t[32][33];
    const int bn = blockIdx.x * 32, bk = blockIdx.y * 32;
    const int lx = threadIdx.x & 31, ly = threadIdx.x >> 5;
#pragma unroll
    for (int i = 0; i < 32; i += 8)
        t[ly + i][lx] = W[(size_t)(bk + ly + i) * N + bn + lx];
    __syncthreads();
#pragma unroll
    for (int i = 0; i < 32; i += 8) {
        float v = t[lx][ly + i];
        size_t o = (size_t)(bn + ly + i) * K + bk + lx;
        if constexpr (SPLIT) {
            _Float16 hi = (_Float16)v;
            _Float16 lo = (_Float16)((v - (float)hi) * 4096.f);
            ((_Float16*)Th)[o] = hi;
            ((_Float16*)Tl)[o] = lo;
        } else {
            ((short*)Th)[o] = f2bf(v);
        }
    }
}

// ---------------------------------------------------------------------------
// Codebook prep: f32 [4][256][64] -> fp16 hi/lo [4][256][64] PRE-SWIZZLED
// (slot s of code c holds dims (s ^ (c&7))*8 .. +8) + f32 cnorm [4][256].
// ---------------------------------------------------------------------------
__global__ __launch_bounds__(256) void prep_cb(
    const float* __restrict__ cb, _Float16* __restrict__ ch,
    _Float16* __restrict__ cl, float* __restrict__ cn)
{
    const int lvl = blockIdx.x;
    const int code = threadIdx.x;
    const float* src = cb + ((size_t)lvl * 256 + code) * 64;
    _Float16* dh = ch + ((size_t)lvl * 256 + code) * 64;
    _Float16* dl = cl + ((size_t)lvl * 256 + code) * 64;
    float s = 0.f;
#pragma unroll
    for (int d = 0; d < 64; ++d) s += src[d] * src[d];
    cn[lvl * 256 + code] = s;
#pragma unroll
    for (int slot = 0; slot < 8; ++slot) {
        int ss = slot ^ (code & 7);
#pragma unroll
        for (int i = 0; i < 8; ++i) {
            float v = src[ss * 8 + i];
            _Float16 h = (_Float16)v;
            dh[slot * 8 + i] = h;
            dl[slot * 8 + i] = (_Float16)((v - (float)h) * 4096.f);
        }
    }
}

// ---------------------------------------------------------------------------
// MFMA residual quantizer (unchanged — measured off top-5).
// ---------------------------------------------------------------------------
__global__ __launch_bounds__(256, 2) void rq_mfma(
    const float* __restrict__ z,
    const _Float16* __restrict__ cbh_g, const _Float16* __restrict__ cbl_g,
    const float* __restrict__ cnorm_g,
    short* __restrict__ xqb, float* __restrict__ idx_out,
    float* __restrict__ loss1)
{
    __shared__ __align__(16) char sH[32768];
    __shared__ __align__(16) char sL[32768];
    __shared__ __align__(16) float sCN[256];

    const int tid  = threadIdx.x;
    const int lane = tid & 63;
    const int wave = tid >> 6;
    const int l15  = lane & 15;
    const int kgrp = lane >> 4;
    const int d0   = kgrp * 8;

    const size_t rowbase = (size_t)blockIdx.x * 256 + wave * 64;

    float rf[4][16];
#pragma unroll
    for (int t = 0; t < 4; ++t) {
        const float* zr = z + (rowbase + t * 16 + l15) * 64;
#pragma unroll
        for (int kf = 0; kf < 2; ++kf) {
            float4 v0 = *(const float4*)(zr + kf * 32 + d0);
            float4 v1 = *(const float4*)(zr + kf * 32 + d0 + 4);
            rf[t][kf * 8 + 0] = v0.x; rf[t][kf * 8 + 1] = v0.y;
            rf[t][kf * 8 + 2] = v0.z; rf[t][kf * 8 + 3] = v0.w;
            rf[t][kf * 8 + 4] = v1.x; rf[t][kf * 8 + 5] = v1.y;
            rf[t][kf * 8 + 6] = v1.z; rf[t][kf * 8 + 7] = v1.w;
        }
    }

    float lsum = 0.f;

    for (int lvl = 0; lvl < 4; ++lvl) {
        __syncthreads();
        {
            const char* gh = (const char*)(cbh_g + (size_t)lvl * 16384);
            const char* gl = (const char*)(cbl_g + (size_t)lvl * 16384);
            const char* gc = (const char*)(cnorm_g + lvl * 256);
            for (int i = wave; i < 65; i += 4) {
                if (i < 32)      gload16(gh + (size_t)i * 1024 + lane * 16, sH + i * 1024);
                else if (i < 64) gload16(gl + (size_t)(i - 32) * 1024 + lane * 16, sL + (i - 32) * 1024);
                else             gload16(gc + lane * 16, (char*)sCN);
            }
        }
        __syncthreads();

        float cn[16];
#pragma unroll
        for (int nf = 0; nf < 16; ++nf) cn[nf] = sCN[nf * 16 + l15];

        for (int t = 0; t < 4; ++t) {
            f16x8 rh0, rh1, rl0, rl1;
#pragma unroll
            for (int i = 0; i < 8; ++i) {
                _Float16 h = (_Float16)rf[t][i];
                rh0[i] = h;
                rl0[i] = (_Float16)((rf[t][i] - (float)h) * 4096.f);
                _Float16 h1 = (_Float16)rf[t][8 + i];
                rh1[i] = h1;
                rl1[i] = (_Float16)((rf[t][8 + i] - (float)h1) * 4096.f);
            }

            float dmin[4]; int imin[4];
#pragma unroll
            for (int j = 0; j < 4; ++j) { dmin[j] = FLT_MAX; imin[j] = 0; }

#pragma unroll
            for (int half = 0; half < 2; ++half) {
                f32x4 a1[8], a2[8];
#pragma unroll
                for (int q = 0; q < 8; ++q) {
                    a1[q] = f32x4{0.f, 0.f, 0.f, 0.f};
                    a2[q] = f32x4{0.f, 0.f, 0.f, 0.f};
                }
#pragma unroll
                for (int q = 0; q < 8; ++q) {
                    int code = (half * 8 + q) * 16 + l15;
                    int sw = (code & 7);
                    const char* ph0 = sH + code * 128 + (((kgrp    ) ^ sw) << 4);
                    const char* ph1 = sH + code * 128 + (((kgrp + 4) ^ sw) << 4);
                    const char* pl0 = sL + code * 128 + (((kgrp    ) ^ sw) << 4);
                    const char* pl1 = sL + code * 128 + (((kgrp + 4) ^ sw) << 4);
                    f16x8 bh_0 = *(const f16x8*)ph0, bh_1 = *(const f16x8*)ph1;
                    f16x8 bl_0 = *(const f16x8*)pl0, bl_1 = *(const f16x8*)pl1;
                    a1[q] = mfma32(rh0, bh_0, a1[q]);
                    a2[q] = mfma32(rl0, bh_0, a2[q]);
                    a2[q] = mfma32(rh0, bl_0, a2[q]);
                    a1[q] = mfma32(rh1, bh_1, a1[q]);
                    a2[q] = mfma32(rl1, bh_1, a2[q]);
                    a2[q] = mfma32(rh1, bl_1, a2[q]);
                }
#pragma unroll
                for (int q = 0; q < 8; ++q) {
                    int nf = half * 8 + q;
                    int code = nf * 16 + l15;
#pragma unroll
                    for (int j = 0; j < 4; ++j) {
                        float dot = fmaf(a2[q][j], (1.f / 4096.f), a1[q][j]);
                        float d = fmaf(dot, -2.f, cn[nf]);
                        bool better = (d < dmin[j]);
                        dmin[j] = better ? d : dmin[j];
                        imin[j] = better ? code : imin[j];
                    }
                }
            }

#pragma unroll
            for (int m = 1; m < 16; m <<= 1) {
#pragma unroll
                for (int j = 0; j < 4; ++j) {
                    float d2 = __shfl_xor(dmin[j], m);
                    int   i2 = __shfl_xor(imin[j], m);
                    bool better = (d2 < dmin[j]) || (d2 == dmin[j] && i2 < imin[j]);
                    dmin[j] = better ? d2 : dmin[j];
                    imin[j] = better ? i2 : imin[j];
                }
            }

            if (l15 == 0) {
#pragma unroll
                for (int j = 0; j < 4; ++j) {
                    size_t row = rowbase + t * 16 + kgrp * 4 + j;
                    idx_out[row * 4 + lvl] = (float)imin[j];
                }
            }

            int srcl = (l15 >> 2) << 4;
            int b0 = __shfl(imin[0], srcl);
            int b1 = __shfl(imin[1], srcl);
            int b2 = __shfl(imin[2], srcl);
            int b3 = __shfl(imin[3], srcl);
            int jj = l15 & 3;
            int bestRow = (jj & 2) ? ((jj & 1) ? b3 : b2) : ((jj & 1) ? b1 : b0);

            int sw = (bestRow & 7);
#pragma unroll
            for (int kf = 0; kf < 2; ++kf) {
                int slot = kgrp + kf * 4;
                f16x8 eh = *(const f16x8*)(sH + bestRow * 128 + ((slot ^ sw) << 4));
                f16x8 el = *(const f16x8*)(sL + bestRow * 128 + ((slot ^ sw) << 4));
#pragma unroll
                for (int i = 0; i < 8; ++i) {
                    float ev = fmaf((float)el[i], (1.f / 4096.f), (float)eh[i]);
                    float rn = rf[t][kf * 8 + i] - ev;
                    lsum += rn * rn;
                    rf[t][kf * 8 + i] = rn;
                }
            }
        }
    }

#pragma unroll
    for (int t = 0; t < 4; ++t) {
        size_t row = rowbase + t * 16 + l15;
        const float* zr = z + row * 64;
        short* xr = xqb + row * 64;
#pragma unroll
        for (int kf = 0; kf < 2; ++kf) {
            float4 v0 = *(const float4*)(zr + kf * 32 + d0);
            float4 v1 = *(const float4*)(zr + kf * 32 + d0 + 4);
            float vv[8] = {v0.x, v0.y, v0.z, v0.w, v1.x, v1.y, v1.z, v1.w};
            short ob[8];
#pragma unroll
            for (int i = 0; i < 8; ++i)
                ob[i] = f2bf(vv[i] - rf[t][kf * 8 + i]);
            *(s16x8*)(xr + kf * 32 + d0) = *(s16x8*)ob;
        }
    }

#pragma unroll
    for (int off = 32; off > 0; off >>= 1)
        lsum += __shfl_down(lsum, off);
    if (lane == 0) atomicAdd(loss1, lsum);
}

__global__ void finalize_loss(const float* __restrict__ loss1, float* __restrict__ rq)
{
    if (threadIdx.x == 0)
        rq[0] = 1.25f * loss1[0] / (4.0f * (float)NROW * 64.0f);
}

extern "C" void kernel_launch(void* const* d_in, const int* in_sizes, int n_in,
                              void* d_out, int out_size, void* d_ws, size_t ws_size,
                              hipStream_t stream)
{
    const float* ew0 = (const float*)d_in[0];
    const float* eb0 = (const float*)d_in[1];
    const float* ew1 = (const float*)d_in[2];
    const float* eb1 = (const float*)d_in[3];
    const float* ew2 = (const float*)d_in[4];
    const float* eb2 = (const float*)d_in[5];
    const float* dw0 = (const float*)d_in[6];
    const float* db0 = (const float*)d_in[7];
    const float* dw1 = (const float*)d_in[8];
    const float* db1 = (const float*)d_in[9];
    const float* dw2 = (const float*)d_in[10];
    const float* db2 = (const float*)d_in[11];
    const float* cb  = (const float*)d_in[12];
    const float* x   = (const float*)d_in[13];

    const size_t N = NROW;
    char* w = (char*)d_ws;
    _Float16* h1h = (_Float16*)w;                 w += N * 512 * 2;
    _Float16* h1l = (_Float16*)w;                 w += N * 512 * 2;
    _Float16* h2h = (_Float16*)w;                 w += N * 256 * 2;
    _Float16* h2l = (_Float16*)w;                 w += N * 256 * 2;
    float*    z   = (float*)w;                    w += N * 64 * 4;
    short*    xqb = (short*)w;                    w += N * 64 * 2;
    _Float16* we0h = (_Float16*)w;                w += 512 * 768 * 2;
    _Float16* we0l = (_Float16*)w;                w += 512 * 768 * 2;
    _Float16* we1h = (_Float16*)w;                w += 256 * 512 * 2;
    _Float16* we1l = (_Float16*)w;                w += 256 * 512 * 2;
    _Float16* we2h = (_Float16*)w;                w += 64 * 256 * 2;
    _Float16* we2l = (_Float16*)w;                w += 64 * 256 * 2;
    short*    wd0  = (short*)w;                   w += 256 * 64 * 2;
    short*    wd1  = (short*)w;                   w += 512 * 256 * 2;
    short*    wd2  = (short*)w;                   w += 768 * 512 * 2;
    float*    loss1 = (float*)w;                  w += 256;
    _Float16* cbh_g = (_Float16*)w;               w += 4 * 256 * 64 * 2;
    _Float16* cbl_g = (_Float16*)w;               w += 4 * 256 * 64 * 2;
    float*    cnorm_g = (float*)w;                w += 4 * 256 * 4;

    float* out  = (float*)d_out;                  // N*768
    float* rq   = out + N * 768;                  // 1
    float* idxf = rq + 1;                         // N*4

    _Float16* xh = (_Float16*)d_out;
    _Float16* xl = xh + N * 768;

    hipMemsetAsync(loss1, 0, sizeof(float), stream);

    dim3 blk(256);
    prep_x<<<dim3(2048), blk, 0, stream>>>(x, xh, xl);
    prep_cb<<<dim3(4), blk, 0, stream>>>(cb, cbh_g, cbl_g, cnorm_g);
    prep_w<true ><<<dim3(512/32, 768/32), blk, 0, stream>>>(ew0, we0h, we0l, 768, 512);
    prep_w<true ><<<dim3(256/32, 512/32), blk, 0, stream>>>(ew1, we1h, we1l, 512, 256);
    prep_w<true ><<<dim3( 64/32, 256/32), blk, 0, stream>>>(ew2, we2h, we2l, 256,  64);
    prep_w<false><<<dim3(256/32,  64/32), blk, 0, stream>>>(dw0, wd0, nullptr,  64, 256);
    prep_w<false><<<dim3(512/32, 256/32), blk, 0, stream>>>(dw1, wd1, nullptr, 256, 512);
    prep_w<false><<<dim3(768/32, 512/32), blk, 0, stream>>>(dw2, wd2, nullptr, 512, 768);

    // encoder: fp16-split MFMA, BK=64; E0/E1 128x128, E2 128x64
    mm_mfma<_Float16, true, 1, 128, 128, 64, true ><<<dim3(4, N/128), blk, 0, stream>>>(
        xh, xl, we0h, we0l, eb0, h1h, h1l, (int)N, 512, 768);
    mm_mfma<_Float16, true, 1, 128, 128, 64, true ><<<dim3(2, N/128), blk, 0, stream>>>(
        h1h, h1l, we1h, we1l, eb1, h2h, h2l, (int)N, 256, 512);
    mm_mfma<_Float16, true, 0, 128, 64, 64, false><<<dim3(1, N/128), blk, 0, stream>>>(
        h2h, h2l, we2h, we2l, eb2, z, nullptr, (int)N, 64, 256);

    // MFMA residual quantization
    rq_mfma<<<dim3(N/256), blk, 0, stream>>>(z, cbh_g, cbl_g, cnorm_g, xqb, idxf, loss1);
    finalize_loss<<<dim3(1), dim3(64), 0, stream>>>(loss1, rq);

    // decoder: bf16 MFMA, 128x128 tiles BK=64, coalesced epilogue
    short* h2b = (short*)h2h;
    short* h1b = (short*)h1h;
    mm_mfma<short, false, 2, 128, 128, 64, true ><<<dim3(2, N/128), blk, 0, stream>>>(
        xqb, nullptr, wd0, nullptr, db0, h2b, nullptr, (int)N, 256, 64);
    mm_mfma<short, false, 2, 128, 128, 64, true ><<<dim3(4, N/128), blk, 0, stream>>>(
        h2b, nullptr, wd1, nullptr, db1, h1b, nullptr, (int)N, 512, 256);
    mm_mfma<short, false, 0, 128, 128, 64, false><<<dim3(6, N/128), blk, 0, stream>>>(
        h1b, nullptr, wd2, nullptr, db2, out, nullptr, (int)N, 768, 512);
}

// Round 14
// 1076.538 us; speedup vs baseline: 4.3333x; 1.1765x over previous
//
#include <hip/hip_runtime.h>
#include <hip/hip_bf16.h>
#include <float.h>
#include <type_traits>

#define NROW 131072

using f16x8 = __attribute__((ext_vector_type(8))) _Float16;
using f16x4 = __attribute__((ext_vector_type(4))) _Float16;
using s16x8 = __attribute__((ext_vector_type(8))) short;
using f32x4 = __attribute__((ext_vector_type(4))) float;

__device__ __forceinline__ f32x4 mfma32(f16x8 a, f16x8 b, f32x4 c) {
    return __builtin_amdgcn_mfma_f32_16x16x32_f16(a, b, c, 0, 0, 0);
}
__device__ __forceinline__ f32x4 mfma32(s16x8 a, s16x8 b, f32x4 c) {
    return __builtin_amdgcn_mfma_f32_16x16x32_bf16(a, b, c, 0, 0, 0);
}

__device__ __forceinline__ short f2bf(float f) {
    unsigned u = __builtin_bit_cast(unsigned, f);
    u += 0x7fffu + ((u >> 16) & 1u);
    return (short)(u >> 16);
}

__device__ __forceinline__ void gload16(const void* g, void* l) {
    __builtin_amdgcn_global_load_lds(
        (const __attribute__((address_space(1))) void*)g,
        (__attribute__((address_space(3))) void*)l, 16, 0, 0);
}

// ---------------------------------------------------------------------------
// MFMA GEMM v10 == r10's v7 verbatim (measured best config, reproduced twice).
// Session lessons: single-buffer schedule beats source-level dbuf (r8);
// SPLIT 128x128 BK=64 best for E0/E1; bf16 128x128 BK=64 bound 4 for decoder
// (256-row tiles spill at bound 3, r9/r12; BK=32+bound4 spills SPLIT, r11);
// 0-conflict XOR slot swizzle (inverse on global source, rule 21);
// coalesced LDS-staged epilogue (exact HBM writes, r10); XCD remap.
// ---------------------------------------------------------------------------
template<typename ET, bool SPLIT, int OUT, int BM, int BN, int BK, bool RELU>
__global__ __launch_bounds__(256,
    ((BM + BN) * (SPLIT ? BK * 4 : BK * 2)) <= 32768 ? 4 :
    (((BM + BN) * (SPLIT ? BK * 4 : BK * 2)) <= 49152 ? 3 : 2))
void mm_mfma(
    const ET* __restrict__ Ah, const ET* __restrict__ Al,
    const ET* __restrict__ Bh, const ET* __restrict__ Bl,
    const float* __restrict__ bias,
    void* __restrict__ O0, void* __restrict__ O1,
    int M, int N, int K)
{
    constexpr int WTM = BM / 2, WTN = BN / 2;
    constexpr int MF = WTM / 16, NF = WTN / 16;
    constexpr int KS = BK / 32;
    constexpr int RB = SPLIT ? BK * 4 : BK * 2;   // row bytes
    constexpr int SLOTS = RB / 16;
    constexpr int SMASK = SLOTS - 1;
    constexpr int RPI = 1024 / RB;                // rows per staging inst
    constexpr int IA = BM * RB / 1024;
    constexpr int IB = BN * RB / 1024;
    constexpr int IT = IA + IB;
    constexpr int IPW = IT / 4;
    static_assert(IT % 4 == 0, "staging insts must split across 4 waves");
    using VT = typename std::conditional<std::is_same<ET, _Float16>::value,
                                         f16x8, s16x8>::type;

    __shared__ __align__(16) char smem[(BM + BN) * RB];

    const int tid  = threadIdx.x;
    const int lane = tid & 63;
    const int wave = tid >> 6;
    const int wm = wave >> 1, wn = wave & 1;

    // XCD-chunked bijective remap (all grids have nwg % 8 == 0)
    int gx = gridDim.x, nwg = gx * gridDim.y;
    int id = blockIdx.y * gx + blockIdx.x;
    int l  = (nwg & 7) ? id : ((id & 7) * (nwg >> 3) + (id >> 3));
    const int bm = (l / gx) * BM;
    const int bn = (l % gx) * BN;

    // ---- precompute staging pointers (register arrays, static indices)
    const int r_loc = lane / SLOTS;
    const int p     = lane % SLOTS;
    const char* gsrc[IPW];
    int ldst[IPW];
#pragma unroll
    for (int i = 0; i < IPW; ++i) {
        int inst = wave * IPW + i;
        bool isA = inst < IA;
        int li   = isA ? inst : inst - IA;
        int row  = li * RPI + r_loc;
        int g    = p ^ (row & SMASK);
        int grow = (isA ? bm : bn) + row;
        const ET* s; int col;
        if constexpr (SPLIT) {
            s   = (g < SLOTS / 2) ? (isA ? Ah : Bh) : (isA ? Al : Bl);
            col = (g & (SLOTS / 2 - 1)) * 8;
        } else {
            s   = isA ? Ah : Bh;
            col = g * 8;
        }
        gsrc[i] = (const char*)(s + (size_t)grow * K + col);
        ldst[i] = (isA ? 0 : BM * RB) + li * 1024;
    }

    char* sA = smem;
    char* sB = smem + BM * RB;

    f32x4 acc1[MF][NF];
    f32x4 acc2[SPLIT ? MF : 1][SPLIT ? NF : 1];
#pragma unroll
    for (int m = 0; m < MF; ++m)
#pragma unroll
        for (int n = 0; n < NF; ++n) {
            acc1[m][n] = f32x4{0.f, 0.f, 0.f, 0.f};
            if constexpr (SPLIT) acc2[m][n] = f32x4{0.f, 0.f, 0.f, 0.f};
        }

    const int kg  = lane >> 4;     // k-group 0..3
    const int l15 = lane & 15;

    for (int k0 = 0; k0 < K; k0 += BK) {
#pragma unroll
        for (int i = 0; i < IPW; ++i)
            gload16(gsrc[i] + (size_t)k0 * sizeof(ET), smem + ldst[i]);
        __syncthreads();
#pragma unroll
        for (int ks = 0; ks < KS; ++ks) {
            const int hslot = ks * 4 + kg;
            VT bh_[NF]; VT bl_[SPLIT ? NF : 1];
#pragma unroll
            for (int n = 0; n < NF; ++n) {
                int nr = wn * WTN + n * 16 + l15;
                bh_[n] = *(const VT*)(sB + nr * RB + ((hslot ^ (nr & SMASK)) << 4));
                if constexpr (SPLIT)
                    bl_[n] = *(const VT*)(sB + nr * RB +
                              (((SLOTS / 2 + hslot) ^ (nr & SMASK)) << 4));
            }
#pragma unroll
            for (int m = 0; m < MF; ++m) {
                int mr = wm * WTM + m * 16 + l15;
                VT a_h = *(const VT*)(sA + mr * RB + ((hslot ^ (mr & SMASK)) << 4));
                VT a_l;
                if constexpr (SPLIT)
                    a_l = *(const VT*)(sA + mr * RB +
                          (((SLOTS / 2 + hslot) ^ (mr & SMASK)) << 4));
#pragma unroll
                for (int n = 0; n < NF; ++n) {
                    acc1[m][n] = mfma32(a_h, bh_[n], acc1[m][n]);
                    if constexpr (SPLIT) {
                        acc2[m][n] = mfma32(a_l, bh_[n], acc2[m][n]);
                        acc2[m][n] = mfma32(a_h, bl_[n], acc2[m][n]);
                    }
                }
            }
        }
        __syncthreads();
    }

    // ---------------- epilogue: LDS-staged coalesced stores ----------------
    constexpr int OELT = (OUT == 0) ? 4 : 2;      // output element bytes
    constexpr int ROWB = WTN * OELT;              // logical row bytes
    constexpr int RSTR = ROWB + 16;               // padded stride
    constexpr int NRG  = (OUT == 1) ? 2 : 1;
    constexpr int SCR  = 16 * RSTR * NRG;         // per-wave scratch bytes
    char* wscr = smem + wave * SCR;
    const int colb = bn + wn * WTN;

#pragma unroll
    for (int m = 0; m < MF; ++m) {
#pragma unroll
        for (int n = 0; n < NF; ++n) {
            int cl = n * 16 + l15;
            float bv = bias[colb + cl];
            f32x4 v = acc1[m][n];
            if constexpr (SPLIT) {
                f32x4 v2 = acc2[m][n];
#pragma unroll
                for (int r = 0; r < 4; ++r) v[r] += v2[r] * (1.0f / 4096.0f);
            }
#pragma unroll
            for (int r = 0; r < 4; ++r) {
                float f = v[r] + bv;
                if constexpr (RELU) f = fmaxf(f, 0.f);
                int lr = kg * 4 + r;
                if constexpr (OUT == 0) {
                    *(float*)(wscr + lr * RSTR + cl * 4) = f;
                } else if constexpr (OUT == 1) {
                    _Float16 hi = (_Float16)f;
                    _Float16 lo = (_Float16)((f - (float)hi) * 4096.f);
                    *(_Float16*)(wscr + lr * RSTR + cl * 2) = hi;
                    *(_Float16*)(wscr + 16 * RSTR + lr * RSTR + cl * 2) = lo;
                } else {
                    *(short*)(wscr + lr * RSTR + cl * 2) = f2bf(f);
                }
            }
        }
        asm volatile("s_waitcnt lgkmcnt(0)" ::: "memory");
        __builtin_amdgcn_sched_barrier(0);

        constexpr int LPR = ROWB / 16;
        constexpr int RPT = 64 / LPR;
        const int rr = lane / LPR;
        const int jj = lane % LPR;
#pragma unroll
        for (int g = 0; g < 16 / RPT; ++g) {
            int lr = g * RPT + rr;
            size_t grow = (size_t)(bm + wm * WTM + m * 16 + lr);
            if constexpr (OUT == 0) {
                float4 vv = *(const float4*)(wscr + lr * RSTR + jj * 16);
                *(float4*)((float*)O0 + grow * N + colb + jj * 4) = vv;
            } else if constexpr (OUT == 1) {
                f16x8 hv = *(const f16x8*)(wscr + lr * RSTR + jj * 16);
                f16x8 lv = *(const f16x8*)(wscr + 16 * RSTR + lr * RSTR + jj * 16);
                *(f16x8*)((_Float16*)O0 + grow * N + colb + jj * 8) = hv;
                *(f16x8*)((_Float16*)O1 + grow * N + colb + jj * 8) = lv;
            } else {
                s16x8 vv = *(const s16x8*)(wscr + lr * RSTR + jj * 16);
                *(s16x8*)((short*)O0 + grow * N + colb + jj * 8) = vv;
            }
        }
        asm volatile("s_waitcnt lgkmcnt(0)" ::: "memory");
        __builtin_amdgcn_sched_barrier(0);
    }
}

// ---------------------------------------------------------------------------
// x (f32) -> xh, xl (fp16, lo pre-scaled by 4096)
// ---------------------------------------------------------------------------
__global__ __launch_bounds__(256) void prep_x(
    const float* __restrict__ x, _Float16* __restrict__ xh, _Float16* __restrict__ xl)
{
    const size_t total = (size_t)NROW * 768 / 4;
    for (size_t i = (size_t)blockIdx.x * 256 + threadIdx.x; i < total;
         i += (size_t)gridDim.x * 256) {
        float4 v = ((const float4*)x)[i];
        f16x4 h, ll;
        h[0] = (_Float16)v.x; h[1] = (_Float16)v.y;
        h[2] = (_Float16)v.z; h[3] = (_Float16)v.w;
        ll[0] = (_Float16)((v.x - (float)h[0]) * 4096.f);
        ll[1] = (_Float16)((v.y - (float)h[1]) * 4096.f);
        ll[2] = (_Float16)((v.z - (float)h[2]) * 4096.f);
        ll[3] = (_Float16)((v.w - (float)h[3]) * 4096.f);
        ((f16x4*)xh)[i] = h;
        ((f16x4*)xl)[i] = ll;
    }
}

// ---------------------------------------------------------------------------
// W [K][N] f32 -> transposed Th/Tl [N][K] (fp16 split or bf16)
// ---------------------------------------------------------------------------
template<bool SPLIT>
__global__ __launch_bounds__(256) void prep_w(
    const float* __restrict__ W, void* __restrict__ Th, void* __restrict__ Tl,
    int K, int N)
{
    __shared__ float t[32][33];
    const int bn = blockIdx.x * 32, bk = blockIdx.y * 32;
    const int lx = threadIdx.x & 31, ly = threadIdx.x >> 5;
#pragma unroll
    for (int i = 0; i < 32; i += 8)
        t[ly + i][lx] = W[(size_t)(bk + ly + i) * N + bn + lx];
    __syncthreads();
#pragma unroll
    for (int i = 0; i < 32; i += 8) {
        float v = t[lx][ly + i];
        size_t o = (size_t)(bn + ly + i) * K + bk + lx;
        if constexpr (SPLIT) {
            _Float16 hi = (_Float16)v;
            _Float16 lo = (_Float16)((v - (float)hi) * 4096.f);
            ((_Float16*)Th)[o] = hi;
            ((_Float16*)Tl)[o] = lo;
        } else {
            ((short*)Th)[o] = f2bf(v);
        }
    }
}

// ---------------------------------------------------------------------------
// Codebook prep: f32 [4][256][64] -> fp16 hi/lo [4][256][64] PRE-SWIZZLED
// (slot s of code c holds dims (s ^ (c&7))*8 .. +8) + f32 cnorm [4][256].
// ---------------------------------------------------------------------------
__global__ __launch_bounds__(256) void prep_cb(
    const float* __restrict__ cb, _Float16* __restrict__ ch,
    _Float16* __restrict__ cl, float* __restrict__ cn)
{
    const int lvl = blockIdx.x;
    const int code = threadIdx.x;
    const float* src = cb + ((size_t)lvl * 256 + code) * 64;
    _Float16* dh = ch + ((size_t)lvl * 256 + code) * 64;
    _Float16* dl = cl + ((size_t)lvl * 256 + code) * 64;
    float s = 0.f;
#pragma unroll
    for (int d = 0; d < 64; ++d) s += src[d] * src[d];
    cn[lvl * 256 + code] = s;
#pragma unroll
    for (int slot = 0; slot < 8; ++slot) {
        int ss = slot ^ (code & 7);
#pragma unroll
        for (int i = 0; i < 8; ++i) {
            float v = src[ss * 8 + i];
            _Float16 h = (_Float16)v;
            dh[slot * 8 + i] = h;
            dl[slot * 8 + i] = (_Float16)((v - (float)h) * 4096.f);
        }
    }
}

// ---------------------------------------------------------------------------
// MFMA residual quantizer. r13 finding: the main per-level tile loop was NOT
// unrolled -> rf[t][..] runtime-indexed -> rf lived in SCRATCH (rule #20):
// 738MB FETCH + 481MB WRITE of spill traffic, 399us. Fix: #pragma unroll.
// ---------------------------------------------------------------------------
__global__ __launch_bounds__(256, 2) void rq_mfma(
    const float* __restrict__ z,
    const _Float16* __restrict__ cbh_g, const _Float16* __restrict__ cbl_g,
    const float* __restrict__ cnorm_g,
    short* __restrict__ xqb, float* __restrict__ idx_out,
    float* __restrict__ loss1)
{
    __shared__ __align__(16) char sH[32768];
    __shared__ __align__(16) char sL[32768];
    __shared__ __align__(16) float sCN[256];

    const int tid  = threadIdx.x;
    const int lane = tid & 63;
    const int wave = tid >> 6;
    const int l15  = lane & 15;
    const int kgrp = lane >> 4;
    const int d0   = kgrp * 8;

    const size_t rowbase = (size_t)blockIdx.x * 256 + wave * 64;

    float rf[4][16];
#pragma unroll
    for (int t = 0; t < 4; ++t) {
        const float* zr = z + (rowbase + t * 16 + l15) * 64;
#pragma unroll
        for (int kf = 0; kf < 2; ++kf) {
            float4 v0 = *(const float4*)(zr + kf * 32 + d0);
            float4 v1 = *(const float4*)(zr + kf * 32 + d0 + 4);
            rf[t][kf * 8 + 0] = v0.x; rf[t][kf * 8 + 1] = v0.y;
            rf[t][kf * 8 + 2] = v0.z; rf[t][kf * 8 + 3] = v0.w;
            rf[t][kf * 8 + 4] = v1.x; rf[t][kf * 8 + 5] = v1.y;
            rf[t][kf * 8 + 6] = v1.z; rf[t][kf * 8 + 7] = v1.w;
        }
    }

    float lsum = 0.f;

    for (int lvl = 0; lvl < 4; ++lvl) {
        __syncthreads();
        {
            const char* gh = (const char*)(cbh_g + (size_t)lvl * 16384);
            const char* gl = (const char*)(cbl_g + (size_t)lvl * 16384);
            const char* gc = (const char*)(cnorm_g + lvl * 256);
            for (int i = wave; i < 65; i += 4) {
                if (i < 32)      gload16(gh + (size_t)i * 1024 + lane * 16, sH + i * 1024);
                else if (i < 64) gload16(gl + (size_t)(i - 32) * 1024 + lane * 16, sL + (i - 32) * 1024);
                else             gload16(gc + lane * 16, (char*)sCN);
            }
        }
        __syncthreads();

        float cn[16];
#pragma unroll
        for (int nf = 0; nf < 16; ++nf) cn[nf] = sCN[nf * 16 + l15];

#pragma unroll   // CRITICAL (rule #20): keeps rf[t] register-resident
        for (int t = 0; t < 4; ++t) {
            f16x8 rh0, rh1, rl0, rl1;
#pragma unroll
            for (int i = 0; i < 8; ++i) {
                _Float16 h = (_Float16)rf[t][i];
                rh0[i] = h;
                rl0[i] = (_Float16)((rf[t][i] - (float)h) * 4096.f);
                _Float16 h1 = (_Float16)rf[t][8 + i];
                rh1[i] = h1;
                rl1[i] = (_Float16)((rf[t][8 + i] - (float)h1) * 4096.f);
            }

            float dmin[4]; int imin[4];
#pragma unroll
            for (int j = 0; j < 4; ++j) { dmin[j] = FLT_MAX; imin[j] = 0; }

#pragma unroll
            for (int half = 0; half < 2; ++half) {
                f32x4 a1[8], a2[8];
#pragma unroll
                for (int q = 0; q < 8; ++q) {
                    a1[q] = f32x4{0.f, 0.f, 0.f, 0.f};
                    a2[q] = f32x4{0.f, 0.f, 0.f, 0.f};
                }
#pragma unroll
                for (int q = 0; q < 8; ++q) {
                    int code = (half * 8 + q) * 16 + l15;
                    int sw = (code & 7);
                    const char* ph0 = sH + code * 128 + (((kgrp    ) ^ sw) << 4);
                    const char* ph1 = sH + code * 128 + (((kgrp + 4) ^ sw) << 4);
                    const char* pl0 = sL + code * 128 + (((kgrp    ) ^ sw) << 4);
                    const char* pl1 = sL + code * 128 + (((kgrp + 4) ^ sw) << 4);
                    f16x8 bh_0 = *(const f16x8*)ph0, bh_1 = *(const f16x8*)ph1;
                    f16x8 bl_0 = *(const f16x8*)pl0, bl_1 = *(const f16x8*)pl1;
                    a1[q] = mfma32(rh0, bh_0, a1[q]);
                    a2[q] = mfma32(rl0, bh_0, a2[q]);
                    a2[q] = mfma32(rh0, bl_0, a2[q]);
                    a1[q] = mfma32(rh1, bh_1, a1[q]);
                    a2[q] = mfma32(rl1, bh_1, a2[q]);
                    a2[q] = mfma32(rh1, bl_1, a2[q]);
                }
#pragma unroll
                for (int q = 0; q < 8; ++q) {
                    int nf = half * 8 + q;
                    int code = nf * 16 + l15;
#pragma unroll
                    for (int j = 0; j < 4; ++j) {
                        float dot = fmaf(a2[q][j], (1.f / 4096.f), a1[q][j]);
                        float d = fmaf(dot, -2.f, cn[nf]);
                        bool better = (d < dmin[j]);
                        dmin[j] = better ? d : dmin[j];
                        imin[j] = better ? code : imin[j];
                    }
                }
            }

#pragma unroll
            for (int m = 1; m < 16; m <<= 1) {
#pragma unroll
                for (int j = 0; j < 4; ++j) {
                    float d2 = __shfl_xor(dmin[j], m);
                    int   i2 = __shfl_xor(imin[j], m);
                    bool better = (d2 < dmin[j]) || (d2 == dmin[j] && i2 < imin[j]);
                    dmin[j] = better ? d2 : dmin[j];
                    imin[j] = better ? i2 : imin[j];
                }
            }

            if (l15 == 0) {
#pragma unroll
                for (int j = 0; j < 4; ++j) {
                    size_t row = rowbase + t * 16 + kgrp * 4 + j;
                    idx_out[row * 4 + lvl] = (float)imin[j];
                }
            }

            int srcl = (l15 >> 2) << 4;
            int b0 = __shfl(imin[0], srcl);
            int b1 = __shfl(imin[1], srcl);
            int b2 = __shfl(imin[2], srcl);
            int b3 = __shfl(imin[3], srcl);
            int jj = l15 & 3;
            int bestRow = (jj & 2) ? ((jj & 1) ? b3 : b2) : ((jj & 1) ? b1 : b0);

            int sw = (bestRow & 7);
#pragma unroll
            for (int kf = 0; kf < 2; ++kf) {
                int slot = kgrp + kf * 4;
                f16x8 eh = *(const f16x8*)(sH + bestRow * 128 + ((slot ^ sw) << 4));
                f16x8 el = *(const f16x8*)(sL + bestRow * 128 + ((slot ^ sw) << 4));
#pragma unroll
                for (int i = 0; i < 8; ++i) {
                    float ev = fmaf((float)el[i], (1.f / 4096.f), (float)eh[i]);
                    float rn = rf[t][kf * 8 + i] - ev;
                    lsum += rn * rn;
                    rf[t][kf * 8 + i] = rn;
                }
            }
        }
    }

#pragma unroll
    for (int t = 0; t < 4; ++t) {
        size_t row = rowbase + t * 16 + l15;
        const float* zr = z + row * 64;
        short* xr = xqb + row * 64;
#pragma unroll
        for (int kf = 0; kf < 2; ++kf) {
            float4 v0 = *(const float4*)(zr + kf * 32 + d0);
            float4 v1 = *(const float4*)(zr + kf * 32 + d0 + 4);
            float vv[8] = {v0.x, v0.y, v0.z, v0.w, v1.x, v1.y, v1.z, v1.w};
            short ob[8];
#pragma unroll
            for (int i = 0; i < 8; ++i)
                ob[i] = f2bf(vv[i] - rf[t][kf * 8 + i]);
            *(s16x8*)(xr + kf * 32 + d0) = *(s16x8*)ob;
        }
    }

#pragma unroll
    for (int off = 32; off > 0; off >>= 1)
        lsum += __shfl_down(lsum, off);
    if (lane == 0) atomicAdd(loss1, lsum);
}

__global__ void finalize_loss(const float* __restrict__ loss1, float* __restrict__ rq)
{
    if (threadIdx.x == 0)
        rq[0] = 1.25f * loss1[0] / (4.0f * (float)NROW * 64.0f);
}

extern "C" void kernel_launch(void* const* d_in, const int* in_sizes, int n_in,
                              void* d_out, int out_size, void* d_ws, size_t ws_size,
                              hipStream_t stream)
{
    const float* ew0 = (const float*)d_in[0];
    const float* eb0 = (const float*)d_in[1];
    const float* ew1 = (const float*)d_in[2];
    const float* eb1 = (const float*)d_in[3];
    const float* ew2 = (const float*)d_in[4];
    const float* eb2 = (const float*)d_in[5];
    const float* dw0 = (const float*)d_in[6];
    const float* db0 = (const float*)d_in[7];
    const float* dw1 = (const float*)d_in[8];
    const float* db1 = (const float*)d_in[9];
    const float* dw2 = (const float*)d_in[10];
    const float* db2 = (const float*)d_in[11];
    const float* cb  = (const float*)d_in[12];
    const float* x   = (const float*)d_in[13];

    const size_t N = NROW;
    char* w = (char*)d_ws;
    _Float16* h1h = (_Float16*)w;                 w += N * 512 * 2;
    _Float16* h1l = (_Float16*)w;                 w += N * 512 * 2;
    _Float16* h2h = (_Float16*)w;                 w += N * 256 * 2;
    _Float16* h2l = (_Float16*)w;                 w += N * 256 * 2;
    float*    z   = (float*)w;                    w += N * 64 * 4;
    short*    xqb = (short*)w;                    w += N * 64 * 2;
    _Float16* we0h = (_Float16*)w;                w += 512 * 768 * 2;
    _Float16* we0l = (_Float16*)w;                w += 512 * 768 * 2;
    _Float16* we1h = (_Float16*)w;                w += 256 * 512 * 2;
    _Float16* we1l = (_Float16*)w;                w += 256 * 512 * 2;
    _Float16* we2h = (_Float16*)w;                w += 64 * 256 * 2;
    _Float16* we2l = (_Float16*)w;                w += 64 * 256 * 2;
    short*    wd0  = (short*)w;                   w += 256 * 64 * 2;
    short*    wd1  = (short*)w;                   w += 512 * 256 * 2;
    short*    wd2  = (short*)w;                   w += 768 * 512 * 2;
    float*    loss1 = (float*)w;                  w += 256;
    _Float16* cbh_g = (_Float16*)w;               w += 4 * 256 * 64 * 2;
    _Float16* cbl_g = (_Float16*)w;               w += 4 * 256 * 64 * 2;
    float*    cnorm_g = (float*)w;                w += 4 * 256 * 4;

    float* out  = (float*)d_out;                  // N*768
    float* rq   = out + N * 768;                  // 1
    float* idxf = rq + 1;                         // N*4

    _Float16* xh = (_Float16*)d_out;
    _Float16* xl = xh + N * 768;

    hipMemsetAsync(loss1, 0, sizeof(float), stream);

    dim3 blk(256);
    prep_x<<<dim3(2048), blk, 0, stream>>>(x, xh, xl);
    prep_cb<<<dim3(4), blk, 0, stream>>>(cb, cbh_g, cbl_g, cnorm_g);
    prep_w<true ><<<dim3(512/32, 768/32), blk, 0, stream>>>(ew0, we0h, we0l, 768, 512);
    prep_w<true ><<<dim3(256/32, 512/32), blk, 0, stream>>>(ew1, we1h, we1l, 512, 256);
    prep_w<true ><<<dim3( 64/32, 256/32), blk, 0, stream>>>(ew2, we2h, we2l, 256,  64);
    prep_w<false><<<dim3(256/32,  64/32), blk, 0, stream>>>(dw0, wd0, nullptr,  64, 256);
    prep_w<false><<<dim3(512/32, 256/32), blk, 0, stream>>>(dw1, wd1, nullptr, 256, 512);
    prep_w<false><<<dim3(768/32, 512/32), blk, 0, stream>>>(dw2, wd2, nullptr, 512, 768);

    // encoder: fp16-split MFMA, BK=64; E0/E1 128x128, E2 128x64
    mm_mfma<_Float16, true, 1, 128, 128, 64, true ><<<dim3(4, N/128), blk, 0, stream>>>(
        xh, xl, we0h, we0l, eb0, h1h, h1l, (int)N, 512, 768);
    mm_mfma<_Float16, true, 1, 128, 128, 64, true ><<<dim3(2, N/128), blk, 0, stream>>>(
        h1h, h1l, we1h, we1l, eb1, h2h, h2l, (int)N, 256, 512);
    mm_mfma<_Float16, true, 0, 128, 64, 64, false><<<dim3(1, N/128), blk, 0, stream>>>(
        h2h, h2l, we2h, we2l, eb2, z, nullptr, (int)N, 64, 256);

    // MFMA residual quantization
    rq_mfma<<<dim3(N/256), blk, 0, stream>>>(z, cbh_g, cbl_g, cnorm_g, xqb, idxf, loss1);
    finalize_loss<<<dim3(1), dim3(64), 0, stream>>>(loss1, rq);

    // decoder: bf16 MFMA, 128x128 tiles BK=64, coalesced epilogue
    short* h2b = (short*)h2h;
    short* h1b = (short*)h1h;
    mm_mfma<short, false, 2, 128, 128, 64, true ><<<dim3(2, N/128), blk, 0, stream>>>(
        xqb, nullptr, wd0, nullptr, db0, h2b, nullptr, (int)N, 256, 64);
    mm_mfma<short, false, 2, 128, 128, 64, true ><<<dim3(4, N/128), blk, 0, stream>>>(
        h2b, nullptr, wd1, nullptr, db1, h1b, nullptr, (int)N, 512, 256);
    mm_mfma<short, false, 0, 128, 128, 64, false><<<dim3(6, N/128), blk, 0, stream>>>(
        h1b, nullptr, wd2, nullptr, db2, out, nullptr, (int)N, 768, 512);
}

// Round 15
// 1068.910 us; speedup vs baseline: 4.3642x; 1.0071x over previous
//
#include <hip/hip_runtime.h>
#include <hip/hip_bf16.h>
#include <float.h>
#include <type_traits>

#define NROW 131072

using f16x8 = __attribute__((ext_vector_type(8))) _Float16;
using f16x4 = __attribute__((ext_vector_type(4))) _Float16;
using s16x8 = __attribute__((ext_vector_type(8))) short;
using f32x4 = __attribute__((ext_vector_type(4))) float;
using f32x16 = __attribute__((ext_vector_type(16))) float;

__device__ __forceinline__ f32x4 mfma32(f16x8 a, f16x8 b, f32x4 c) {
    return __builtin_amdgcn_mfma_f32_16x16x32_f16(a, b, c, 0, 0, 0);
}
__device__ __forceinline__ f32x4 mfma32(s16x8 a, s16x8 b, f32x4 c) {
    return __builtin_amdgcn_mfma_f32_16x16x32_bf16(a, b, c, 0, 0, 0);
}
__device__ __forceinline__ f32x16 mfma3216(f16x8 a, f16x8 b, f32x16 c) {
    return __builtin_amdgcn_mfma_f32_32x32x16_f16(a, b, c, 0, 0, 0);
}
__device__ __forceinline__ f32x16 mfma3216(s16x8 a, s16x8 b, f32x16 c) {
    return __builtin_amdgcn_mfma_f32_32x32x16_bf16(a, b, c, 0, 0, 0);
}

__device__ __forceinline__ short f2bf(float f) {
    unsigned u = __builtin_bit_cast(unsigned, f);
    u += 0x7fffu + ((u >> 16) & 1u);
    return (short)(u >> 16);
}

__device__ __forceinline__ void gload16(const void* g, void* l) {
    __builtin_amdgcn_global_load_lds(
        (const __attribute__((address_space(1))) void*)g,
        (__attribute__((address_space(3))) void*)l, 16, 0, 0);
}

// ---------------------------------------------------------------------------
// MFMA GEMM v11 = r10/r14 structure (single-buffer schedule, 0-conflict XOR
// slot swizzle w/ inverse on global source, coalesced LDS-staged epilogue,
// XCD remap) with the MFMA shape switched 16x16x32 -> 32x32x16:
// same FLOPs in half the MFMA issues at the faster 32x32 rate
// (ubench 2382 vs 2075 TF), identical LDS traffic and staging path.
// Fragment maps: A/B row=lane&31, k=(lane>>5)*8+j (family-consistent with
// the validated 16x16x32 map); C/D col=lane&31,
// row=(reg&3)+8*(reg>>2)+4*(lane>>5) (guide, HW-verified m74/m101).
// Ledger: no source dbuf (r8); SPLIT needs bound<=2-3 (r11); no 256-row
// tiles at bound>=3 (r9/r12); unroll everything touching reg arrays (r13).
// ---------------------------------------------------------------------------
template<typename ET, bool SPLIT, int OUT, int BM, int BN, int BK, bool RELU>
__global__ __launch_bounds__(256,
    ((BM + BN) * (SPLIT ? BK * 4 : BK * 2)) <= 32768 ? 4 :
    (((BM + BN) * (SPLIT ? BK * 4 : BK * 2)) <= 49152 ? 3 : 2))
void mm_mfma(
    const ET* __restrict__ Ah, const ET* __restrict__ Al,
    const ET* __restrict__ Bh, const ET* __restrict__ Bl,
    const float* __restrict__ bias,
    void* __restrict__ O0, void* __restrict__ O1,
    int M, int N, int K)
{
    constexpr int WTM = BM / 2, WTN = BN / 2;
    constexpr int MF = WTM / 32, NF = WTN / 32;   // 32x32 MFMA tiles
    constexpr int KS = BK / 16;                   // K=16 per MFMA
    constexpr int RB = SPLIT ? BK * 4 : BK * 2;   // row bytes
    constexpr int SLOTS = RB / 16;
    constexpr int SMASK = SLOTS - 1;
    constexpr int RPI = 1024 / RB;                // rows per staging inst
    constexpr int IA = BM * RB / 1024;
    constexpr int IB = BN * RB / 1024;
    constexpr int IT = IA + IB;
    constexpr int IPW = IT / 4;
    static_assert(IT % 4 == 0, "staging insts must split across 4 waves");
    using VT = typename std::conditional<std::is_same<ET, _Float16>::value,
                                         f16x8, s16x8>::type;

    __shared__ __align__(16) char smem[(BM + BN) * RB];

    const int tid  = threadIdx.x;
    const int lane = tid & 63;
    const int wave = tid >> 6;
    const int wm = wave >> 1, wn = wave & 1;
    const int lhalf = lane >> 5;                  // 0/1: k-half within K=16
    const int l31   = lane & 31;                  // row/col within 32

    // XCD-chunked bijective remap (all grids have nwg % 8 == 0)
    int gx = gridDim.x, nwg = gx * gridDim.y;
    int id = blockIdx.y * gx + blockIdx.x;
    int l  = (nwg & 7) ? id : ((id & 7) * (nwg >> 3) + (id >> 3));
    const int bm = (l / gx) * BM;
    const int bn = (l % gx) * BN;

    // ---- precompute staging pointers (register arrays, static indices)
    const int r_loc = lane / SLOTS;
    const int p     = lane % SLOTS;
    const char* gsrc[IPW];
    int ldst[IPW];
#pragma unroll
    for (int i = 0; i < IPW; ++i) {
        int inst = wave * IPW + i;
        bool isA = inst < IA;
        int li   = isA ? inst : inst - IA;
        int row  = li * RPI + r_loc;
        int g    = p ^ (row & SMASK);
        int grow = (isA ? bm : bn) + row;
        const ET* s; int col;
        if constexpr (SPLIT) {
            s   = (g < SLOTS / 2) ? (isA ? Ah : Bh) : (isA ? Al : Bl);
            col = (g & (SLOTS / 2 - 1)) * 8;
        } else {
            s   = isA ? Ah : Bh;
            col = g * 8;
        }
        gsrc[i] = (const char*)(s + (size_t)grow * K + col);
        ldst[i] = (isA ? 0 : BM * RB) + li * 1024;
    }

    char* sA = smem;
    char* sB = smem + BM * RB;

    f32x16 acc1[MF][NF];
    f32x16 acc2[SPLIT ? MF : 1][SPLIT ? NF : 1];
#pragma unroll
    for (int m = 0; m < MF; ++m)
#pragma unroll
        for (int n = 0; n < NF; ++n) {
#pragma unroll
            for (int r = 0; r < 16; ++r) {
                acc1[m][n][r] = 0.f;
                if constexpr (SPLIT) acc2[m][n][r] = 0.f;
            }
        }

    for (int k0 = 0; k0 < K; k0 += BK) {
#pragma unroll
        for (int i = 0; i < IPW; ++i)
            gload16(gsrc[i] + (size_t)k0 * sizeof(ET), smem + ldst[i]);
        __syncthreads();
#pragma unroll
        for (int ks = 0; ks < KS; ++ks) {
            const int hslot = ks * 2 + lhalf;     // 16B slot of this k-half
            VT bh_[NF]; VT bl_[SPLIT ? NF : 1];
#pragma unroll
            for (int n = 0; n < NF; ++n) {
                int nr = wn * WTN + n * 32 + l31;
                bh_[n] = *(const VT*)(sB + nr * RB + ((hslot ^ (nr & SMASK)) << 4));
                if constexpr (SPLIT)
                    bl_[n] = *(const VT*)(sB + nr * RB +
                              (((SLOTS / 2 + hslot) ^ (nr & SMASK)) << 4));
            }
#pragma unroll
            for (int m = 0; m < MF; ++m) {
                int mr = wm * WTM + m * 32 + l31;
                VT a_h = *(const VT*)(sA + mr * RB + ((hslot ^ (mr & SMASK)) << 4));
                VT a_l;
                if constexpr (SPLIT)
                    a_l = *(const VT*)(sA + mr * RB +
                          (((SLOTS / 2 + hslot) ^ (mr & SMASK)) << 4));
#pragma unroll
                for (int n = 0; n < NF; ++n) {
                    acc1[m][n] = mfma3216(a_h, bh_[n], acc1[m][n]);
                    if constexpr (SPLIT) {
                        acc2[m][n] = mfma3216(a_l, bh_[n], acc2[m][n]);
                        acc2[m][n] = mfma3216(a_h, bl_[n], acc2[m][n]);
                    }
                }
            }
        }
        __syncthreads();
    }

    // ---------------- epilogue: LDS-staged coalesced stores ----------------
    // C/D map (guide, HW-verified): col=lane&31,
    // row=(reg&3)+8*(reg>>2)+4*(lane>>5). Scatter 32 rows per m-tile into
    // per-wave padded scratch, then store row-contiguous 16B vectors.
    constexpr int OELT = (OUT == 0) ? 4 : 2;      // output element bytes
    constexpr int ROWB = WTN * OELT;              // logical row bytes
    constexpr int RSTR = ROWB + 16;               // padded stride
    constexpr int NRG  = (OUT == 1) ? 2 : 1;
    constexpr int SCR  = 32 * RSTR * NRG;         // per-wave scratch bytes
    char* wscr = smem + wave * SCR;
    const int colb = bn + wn * WTN;

#pragma unroll
    for (int m = 0; m < MF; ++m) {
#pragma unroll
        for (int n = 0; n < NF; ++n) {
            int cl = n * 32 + l31;
            float bv = bias[colb + cl];
#pragma unroll
            for (int r = 0; r < 16; ++r) {
                float f = acc1[m][n][r];
                if constexpr (SPLIT)
                    f += acc2[m][n][r] * (1.0f / 4096.0f);
                f += bv;
                if constexpr (RELU) f = fmaxf(f, 0.f);
                int lr = (r & 3) + 8 * (r >> 2) + 4 * lhalf;   // 0..31
                if constexpr (OUT == 0) {
                    *(float*)(wscr + lr * RSTR + cl * 4) = f;
                } else if constexpr (OUT == 1) {
                    _Float16 hi = (_Float16)f;
                    _Float16 lo = (_Float16)((f - (float)hi) * 4096.f);
                    *(_Float16*)(wscr + lr * RSTR + cl * 2) = hi;
                    *(_Float16*)(wscr + 32 * RSTR + lr * RSTR + cl * 2) = lo;
                } else {
                    *(short*)(wscr + lr * RSTR + cl * 2) = f2bf(f);
                }
            }
        }
        asm volatile("s_waitcnt lgkmcnt(0)" ::: "memory");
        __builtin_amdgcn_sched_barrier(0);

        constexpr int LPR = ROWB / 16;            // lanes per row
        constexpr int RPT = 64 / LPR;             // rows per store instr
        const int rr = lane / LPR;
        const int jj = lane % LPR;
#pragma unroll
        for (int g = 0; g < 32 / RPT; ++g) {
            int lr = g * RPT + rr;
            size_t grow = (size_t)(bm + wm * WTM + m * 32 + lr);
            if constexpr (OUT == 0) {
                float4 vv = *(const float4*)(wscr + lr * RSTR + jj * 16);
                *(float4*)((float*)O0 + grow * N + colb + jj * 4) = vv;
            } else if constexpr (OUT == 1) {
                f16x8 hv = *(const f16x8*)(wscr + lr * RSTR + jj * 16);
                f16x8 lv = *(const f16x8*)(wscr + 32 * RSTR + lr * RSTR + jj * 16);
                *(f16x8*)((_Float16*)O0 + grow * N + colb + jj * 8) = hv;
                *(f16x8*)((_Float16*)O1 + grow * N + colb + jj * 8) = lv;
            } else {
                s16x8 vv = *(const s16x8*)(wscr + lr * RSTR + jj * 16);
                *(s16x8*)((short*)O0 + grow * N + colb + jj * 8) = vv;
            }
        }
        asm volatile("s_waitcnt lgkmcnt(0)" ::: "memory");
        __builtin_amdgcn_sched_barrier(0);
    }
}

// ---------------------------------------------------------------------------
// x (f32) -> xh, xl (fp16, lo pre-scaled by 4096)
// ---------------------------------------------------------------------------
__global__ __launch_bounds__(256) void prep_x(
    const float* __restrict__ x, _Float16* __restrict__ xh, _Float16* __restrict__ xl)
{
    const size_t total = (size_t)NROW * 768 / 4;
    for (size_t i = (size_t)blockIdx.x * 256 + threadIdx.x; i < total;
         i += (size_t)gridDim.x * 256) {
        float4 v = ((const float4*)x)[i];
        f16x4 h, ll;
        h[0] = (_Float16)v.x; h[1] = (_Float16)v.y;
        h[2] = (_Float16)v.z; h[3] = (_Float16)v.w;
        ll[0] = (_Float16)((v.x - (float)h[0]) * 4096.f);
        ll[1] = (_Float16)((v.y - (float)h[1]) * 4096.f);
        ll[2] = (_Float16)((v.z - (float)h[2]) * 4096.f);
        ll[3] = (_Float16)((v.w - (float)h[3]) * 4096.f);
        ((f16x4*)xh)[i] = h;
        ((f16x4*)xl)[i] = ll;
    }
}

// ---------------------------------------------------------------------------
// W [K][N] f32 -> transposed Th/Tl [N][K] (fp16 split or bf16)
// ---------------------------------------------------------------------------
template<bool SPLIT>
__global__ __launch_bounds__(256) void prep_w(
    const float* __restrict__ W, void* __restrict__ Th, void* __restrict__ Tl,
    int K, int N)
{
    __shared__ float t[32][33];
    const int bn = blockIdx.x * 32, bk = blockIdx.y * 32;
    const int lx = threadIdx.x & 31, ly = threadIdx.x >> 5;
#pragma unroll
    for (int i = 0; i < 32; i += 8)
        t[ly + i][lx] = W[(size_t)(bk + ly + i) * N + bn + lx];
    __syncthreads();
#pragma unroll
    for (int i = 0; i < 32; i += 8) {
        float v = t[lx][ly + i];
        size_t o = (size_t)(bn + ly + i) * K + bk + lx;
        if constexpr (SPLIT) {
            _Float16 hi = (_Float16)v;
            _Float16 lo = (_Float16)((v - (float)hi) * 4096.f);
            ((_Float16*)Th)[o] = hi;
            ((_Float16*)Tl)[o] = lo;
        } else {
            ((short*)Th)[o] = f2bf(v);
        }
    }
}

// ---------------------------------------------------------------------------
// Codebook prep: f32 [4][256][64] -> fp16 hi/lo [4][256][64] PRE-SWIZZLED
// (slot s of code c holds dims (s ^ (c&7))*8 .. +8) + f32 cnorm [4][256].
// ---------------------------------------------------------------------------
__global__ __launch_bounds__(256) void prep_cb(
    const float* __restrict__ cb, _Float16* __restrict__ ch,
    _Float16* __restrict__ cl, float* __restrict__ cn)
{
    const int lvl = blockIdx.x;
    const int code = threadIdx.x;
    const float* src = cb + ((size_t)lvl * 256 + code) * 64;
    _Float16* dh = ch + ((size_t)lvl * 256 + code) * 64;
    _Float16* dl = cl + ((size_t)lvl * 256 + code) * 64;
    float s = 0.f;
#pragma unroll
    for (int d = 0; d < 64; ++d) s += src[d] * src[d];
    cn[lvl * 256 + code] = s;
#pragma unroll
    for (int slot = 0; slot < 8; ++slot) {
        int ss = slot ^ (code & 7);
#pragma unroll
        for (int i = 0; i < 8; ++i) {
            float v = src[ss * 8 + i];
            _Float16 h = (_Float16)v;
            dh[slot * 8 + i] = h;
            dl[slot * 8 + i] = (_Float16)((v - (float)h) * 4096.f);
        }
    }
}

// ---------------------------------------------------------------------------
// MFMA residual quantizer (16x16 shape kept — argmin layout depends on it).
// r13: the per-level tile loop MUST be unrolled (rule #20) else rf spills.
// ---------------------------------------------------------------------------
__global__ __launch_bounds__(256, 2) void rq_mfma(
    const float* __restrict__ z,
    const _Float16* __restrict__ cbh_g, const _Float16* __restrict__ cbl_g,
    const float* __restrict__ cnorm_g,
    short* __restrict__ xqb, float* __restrict__ idx_out,
    float* __restrict__ loss1)
{
    __shared__ __align__(16) char sH[32768];
    __shared__ __align__(16) char sL[32768];
    __shared__ __align__(16) float sCN[256];

    const int tid  = threadIdx.x;
    const int lane = tid & 63;
    const int wave = tid >> 6;
    const int l15  = lane & 15;
    const int kgrp = lane >> 4;
    const int d0   = kgrp * 8;

    const size_t rowbase = (size_t)blockIdx.x * 256 + wave * 64;

    float rf[4][16];
#pragma unroll
    for (int t = 0; t < 4; ++t) {
        const float* zr = z + (rowbase + t * 16 + l15) * 64;
#pragma unroll
        for (int kf = 0; kf < 2; ++kf) {
            float4 v0 = *(const float4*)(zr + kf * 32 + d0);
            float4 v1 = *(const float4*)(zr + kf * 32 + d0 + 4);
            rf[t][kf * 8 + 0] = v0.x; rf[t][kf * 8 + 1] = v0.y;
            rf[t][kf * 8 + 2] = v0.z; rf[t][kf * 8 + 3] = v0.w;
            rf[t][kf * 8 + 4] = v1.x; rf[t][kf * 8 + 5] = v1.y;
            rf[t][kf * 8 + 6] = v1.z; rf[t][kf * 8 + 7] = v1.w;
        }
    }

    float lsum = 0.f;

    for (int lvl = 0; lvl < 4; ++lvl) {
        __syncthreads();
        {
            const char* gh = (const char*)(cbh_g + (size_t)lvl * 16384);
            const char* gl = (const char*)(cbl_g + (size_t)lvl * 16384);
            const char* gc = (const char*)(cnorm_g + lvl * 256);
            for (int i = wave; i < 65; i += 4) {
                if (i < 32)      gload16(gh + (size_t)i * 1024 + lane * 16, sH + i * 1024);
                else if (i < 64) gload16(gl + (size_t)(i - 32) * 1024 + lane * 16, sL + (i - 32) * 1024);
                else             gload16(gc + lane * 16, (char*)sCN);
            }
        }
        __syncthreads();

        float cn[16];
#pragma unroll
        for (int nf = 0; nf < 16; ++nf) cn[nf] = sCN[nf * 16 + l15];

#pragma unroll   // CRITICAL (rule #20): keeps rf[t] register-resident
        for (int t = 0; t < 4; ++t) {
            f16x8 rh0, rh1, rl0, rl1;
#pragma unroll
            for (int i = 0; i < 8; ++i) {
                _Float16 h = (_Float16)rf[t][i];
                rh0[i] = h;
                rl0[i] = (_Float16)((rf[t][i] - (float)h) * 4096.f);
                _Float16 h1 = (_Float16)rf[t][8 + i];
                rh1[i] = h1;
                rl1[i] = (_Float16)((rf[t][8 + i] - (float)h1) * 4096.f);
            }

            float dmin[4]; int imin[4];
#pragma unroll
            for (int j = 0; j < 4; ++j) { dmin[j] = FLT_MAX; imin[j] = 0; }

#pragma unroll
            for (int half = 0; half < 2; ++half) {
                f32x4 a1[8], a2[8];
#pragma unroll
                for (int q = 0; q < 8; ++q) {
                    a1[q] = f32x4{0.f, 0.f, 0.f, 0.f};
                    a2[q] = f32x4{0.f, 0.f, 0.f, 0.f};
                }
#pragma unroll
                for (int q = 0; q < 8; ++q) {
                    int code = (half * 8 + q) * 16 + l15;
                    int sw = (code & 7);
                    const char* ph0 = sH + code * 128 + (((kgrp    ) ^ sw) << 4);
                    const char* ph1 = sH + code * 128 + (((kgrp + 4) ^ sw) << 4);
                    const char* pl0 = sL + code * 128 + (((kgrp    ) ^ sw) << 4);
                    const char* pl1 = sL + code * 128 + (((kgrp + 4) ^ sw) << 4);
                    f16x8 bh_0 = *(const f16x8*)ph0, bh_1 = *(const f16x8*)ph1;
                    f16x8 bl_0 = *(const f16x8*)pl0, bl_1 = *(const f16x8*)pl1;
                    a1[q] = mfma32(rh0, bh_0, a1[q]);
                    a2[q] = mfma32(rl0, bh_0, a2[q]);
                    a2[q] = mfma32(rh0, bl_0, a2[q]);
                    a1[q] = mfma32(rh1, bh_1, a1[q]);
                    a2[q] = mfma32(rl1, bh_1, a2[q]);
                    a2[q] = mfma32(rh1, bl_1, a2[q]);
                }
#pragma unroll
                for (int q = 0; q < 8; ++q) {
                    int nf = half * 8 + q;
                    int code = nf * 16 + l15;
#pragma unroll
                    for (int j = 0; j < 4; ++j) {
                        float dot = fmaf(a2[q][j], (1.f / 4096.f), a1[q][j]);
                        float d = fmaf(dot, -2.f, cn[nf]);
                        bool better = (d < dmin[j]);
                        dmin[j] = better ? d : dmin[j];
                        imin[j] = better ? code : imin[j];
                    }
                }
            }

#pragma unroll
            for (int m = 1; m < 16; m <<= 1) {
#pragma unroll
                for (int j = 0; j < 4; ++j) {
                    float d2 = __shfl_xor(dmin[j], m);
                    int   i2 = __shfl_xor(imin[j], m);
                    bool better = (d2 < dmin[j]) || (d2 == dmin[j] && i2 < imin[j]);
                    dmin[j] = better ? d2 : dmin[j];
                    imin[j] = better ? i2 : imin[j];
                }
            }

            if (l15 == 0) {
#pragma unroll
                for (int j = 0; j < 4; ++j) {
                    size_t row = rowbase + t * 16 + kgrp * 4 + j;
                    idx_out[row * 4 + lvl] = (float)imin[j];
                }
            }

            int srcl = (l15 >> 2) << 4;
            int b0 = __shfl(imin[0], srcl);
            int b1 = __shfl(imin[1], srcl);
            int b2 = __shfl(imin[2], srcl);
            int b3 = __shfl(imin[3], srcl);
            int jj = l15 & 3;
            int bestRow = (jj & 2) ? ((jj & 1) ? b3 : b2) : ((jj & 1) ? b1 : b0);

            int sw = (bestRow & 7);
#pragma unroll
            for (int kf = 0; kf < 2; ++kf) {
                int slot = kgrp + kf * 4;
                f16x8 eh = *(const f16x8*)(sH + bestRow * 128 + ((slot ^ sw) << 4));
                f16x8 el = *(const f16x8*)(sL + bestRow * 128 + ((slot ^ sw) << 4));
#pragma unroll
                for (int i = 0; i < 8; ++i) {
                    float ev = fmaf((float)el[i], (1.f / 4096.f), (float)eh[i]);
                    float rn = rf[t][kf * 8 + i] - ev;
                    lsum += rn * rn;
                    rf[t][kf * 8 + i] = rn;
                }
            }
        }
    }

#pragma unroll
    for (int t = 0; t < 4; ++t) {
        size_t row = rowbase + t * 16 + l15;
        const float* zr = z + row * 64;
        short* xr = xqb + row * 64;
#pragma unroll
        for (int kf = 0; kf < 2; ++kf) {
            float4 v0 = *(const float4*)(zr + kf * 32 + d0);
            float4 v1 = *(const float4*)(zr + kf * 32 + d0 + 4);
            float vv[8] = {v0.x, v0.y, v0.z, v0.w, v1.x, v1.y, v1.z, v1.w};
            short ob[8];
#pragma unroll
            for (int i = 0; i < 8; ++i)
                ob[i] = f2bf(vv[i] - rf[t][kf * 8 + i]);
            *(s16x8*)(xr + kf * 32 + d0) = *(s16x8*)ob;
        }
    }

#pragma unroll
    for (int off = 32; off > 0; off >>= 1)
        lsum += __shfl_down(lsum, off);
    if (lane == 0) atomicAdd(loss1, lsum);
}

__global__ void finalize_loss(const float* __restrict__ loss1, float* __restrict__ rq)
{
    if (threadIdx.x == 0)
        rq[0] = 1.25f * loss1[0] / (4.0f * (float)NROW * 64.0f);
}

extern "C" void kernel_launch(void* const* d_in, const int* in_sizes, int n_in,
                              void* d_out, int out_size, void* d_ws, size_t ws_size,
                              hipStream_t stream)
{
    const float* ew0 = (const float*)d_in[0];
    const float* eb0 = (const float*)d_in[1];
    const float* ew1 = (const float*)d_in[2];
    const float* eb1 = (const float*)d_in[3];
    const float* ew2 = (const float*)d_in[4];
    const float* eb2 = (const float*)d_in[5];
    const float* dw0 = (const float*)d_in[6];
    const float* db0 = (const float*)d_in[7];
    const float* dw1 = (const float*)d_in[8];
    const float* db1 = (const float*)d_in[9];
    const float* dw2 = (const float*)d_in[10];
    const float* db2 = (const float*)d_in[11];
    const float* cb  = (const float*)d_in[12];
    const float* x   = (const float*)d_in[13];

    const size_t N = NROW;
    char* w = (char*)d_ws;
    _Float16* h1h = (_Float16*)w;                 w += N * 512 * 2;
    _Float16* h1l = (_Float16*)w;                 w += N * 512 * 2;
    _Float16* h2h = (_Float16*)w;                 w += N * 256 * 2;
    _Float16* h2l = (_Float16*)w;                 w += N * 256 * 2;
    float*    z   = (float*)w;                    w += N * 64 * 4;
    short*    xqb = (short*)w;                    w += N * 64 * 2;
    _Float16* we0h = (_Float16*)w;                w += 512 * 768 * 2;
    _Float16* we0l = (_Float16*)w;                w += 512 * 768 * 2;
    _Float16* we1h = (_Float16*)w;                w += 256 * 512 * 2;
    _Float16* we1l = (_Float16*)w;                w += 256 * 512 * 2;
    _Float16* we2h = (_Float16*)w;                w += 64 * 256 * 2;
    _Float16* we2l = (_Float16*)w;                w += 64 * 256 * 2;
    short*    wd0  = (short*)w;                   w += 256 * 64 * 2;
    short*    wd1  = (short*)w;                   w += 512 * 256 * 2;
    short*    wd2  = (short*)w;                   w += 768 * 512 * 2;
    float*    loss1 = (float*)w;                  w += 256;
    _Float16* cbh_g = (_Float16*)w;               w += 4 * 256 * 64 * 2;
    _Float16* cbl_g = (_Float16*)w;               w += 4 * 256 * 64 * 2;
    float*    cnorm_g = (float*)w;                w += 4 * 256 * 4;

    float* out  = (float*)d_out;                  // N*768
    float* rq   = out + N * 768;                  // 1
    float* idxf = rq + 1;                         // N*4

    _Float16* xh = (_Float16*)d_out;
    _Float16* xl = xh + N * 768;

    hipMemsetAsync(loss1, 0, sizeof(float), stream);

    dim3 blk(256);
    prep_x<<<dim3(2048), blk, 0, stream>>>(x, xh, xl);
    prep_cb<<<dim3(4), blk, 0, stream>>>(cb, cbh_g, cbl_g, cnorm_g);
    prep_w<true ><<<dim3(512/32, 768/32), blk, 0, stream>>>(ew0, we0h, we0l, 768, 512);
    prep_w<true ><<<dim3(256/32, 512/32), blk, 0, stream>>>(ew1, we1h, we1l, 512, 256);
    prep_w<true ><<<dim3( 64/32, 256/32), blk, 0, stream>>>(ew2, we2h, we2l, 256,  64);
    prep_w<false><<<dim3(256/32,  64/32), blk, 0, stream>>>(dw0, wd0, nullptr,  64, 256);
    prep_w<false><<<dim3(512/32, 256/32), blk, 0, stream>>>(dw1, wd1, nullptr, 256, 512);
    prep_w<false><<<dim3(768/32, 512/32), blk, 0, stream>>>(dw2, wd2, nullptr, 512, 768);

    // encoder: fp16-split MFMA (32x32x16), BK=64; E0/E1 128x128, E2 128x64
    mm_mfma<_Float16, true, 1, 128, 128, 64, true ><<<dim3(4, N/128), blk, 0, stream>>>(
        xh, xl, we0h, we0l, eb0, h1h, h1l, (int)N, 512, 768);
    mm_mfma<_Float16, true, 1, 128, 128, 64, true ><<<dim3(2, N/128), blk, 0, stream>>>(
        h1h, h1l, we1h, we1l, eb1, h2h, h2l, (int)N, 256, 512);
    mm_mfma<_Float16, true, 0, 128, 64, 64, false><<<dim3(1, N/128), blk, 0, stream>>>(
        h2h, h2l, we2h, we2l, eb2, z, nullptr, (int)N, 64, 256);

    // MFMA residual quantization
    rq_mfma<<<dim3(N/256), blk, 0, stream>>>(z, cbh_g, cbl_g, cnorm_g, xqb, idxf, loss1);
    finalize_loss<<<dim3(1), dim3(64), 0, stream>>>(loss1, rq);

    // decoder: bf16 MFMA (32x32x16), 128x128 tiles BK=64, coalesced epilogue
    short* h2b = (short*)h2h;
    short* h1b = (short*)h1h;
    mm_mfma<short, false, 2, 128, 128, 64, true ><<<dim3(2, N/128), blk, 0, stream>>>(
        xqb, nullptr, wd0, nullptr, db0, h2b, nullptr, (int)N, 256, 64);
    mm_mfma<short, false, 2, 128, 128, 64, true ><<<dim3(4, N/128), blk, 0, stream>>>(
        h2b, nullptr, wd1, nullptr, db1, h1b, nullptr, (int)N, 512, 256);
    mm_mfma<short, false, 0, 128, 128, 64, false><<<dim3(6, N/128), blk, 0, stream>>>(
        h1b, nullptr, wd2, nullptr, db2, out, nullptr, (int)N, 768, 512);
}